// Round 15
// baseline (259.038 us; speedup 1.0000x reference)
//
#include <hip/hip_runtime.h>
#include <hip/hip_bf16.h>
#include <math.h>

#define Bc 32
#define Tc 512
#define Cc 256
#define Hc 8
#define BT (Bc * Tc)
#define EPS 1e-5f
#define LDAP 40      // attn LDS row stride (ushorts)
#define LDSW 32      // GEMM LDS row stride (ushorts, 64B rows, XOR-swizzled chunks)
#define CSTRIDE 128  // fixed CSR row stride

typedef __bf16 bf16x8 __attribute__((ext_vector_type(8)));
typedef float f32x4 __attribute__((ext_vector_type(4)));
typedef unsigned short us8_t __attribute__((ext_vector_type(8)));

__device__ inline unsigned short f2bf(float f) {
    unsigned int u = __float_as_uint(f);
    u += 0x7fffu + ((u >> 16) & 1u);
    return (unsigned short)(u >> 16);
}
__device__ inline unsigned short f2bf_fast(float f) {
    __bf16 h = (__bf16)f;
    return __builtin_bit_cast(unsigned short, h);
}
__device__ inline float bf2f(unsigned short u) {
    return __uint_as_float((unsigned int)u << 16);
}

// ---------------------------------------------------------------------------
// Mega-fused prologue (unchanged from R14)
// ---------------------------------------------------------------------------
__global__ void wcvt_fused_kernel(const float* __restrict__ Wr, const float* __restrict__ Wn,
                                  const float* __restrict__ Wq, const float* __restrict__ Wk,
                                  const float* __restrict__ Wv, const float* __restrict__ Wo,
                                  const float* __restrict__ W1, const float* __restrict__ W2,
                                  const float* __restrict__ bq, const float* __restrict__ bk,
                                  const float* __restrict__ bv,
                                  unsigned short* __restrict__ wsq, float* __restrict__ bqkv,
                                  const float* __restrict__ x, const int* __restrict__ idx,
                                  unsigned short* __restrict__ x_bf,
                                  unsigned short* __restrict__ xd_bf,
                                  int* __restrict__ bcnt, int* __restrict__ zbase,
                                  int N, int nzero4) {
    const float scale = 0.17677669529663687f;  // 1/sqrt(32)
    int gid = blockIdx.x * 256 + threadIdx.x;
    const int X0 = 656128 + N * 32;
    const int XZ = X0 + 64;
    if (gid >= XZ) {
        int j = gid - XZ;
        if (j < nzero4) {
            int4 z = {0, 0, 0, 0};
            *(int4*)&zbase[j * 4] = z;
        }
        return;
    }
    if (gid >= X0) {
        int b = gid - X0;
        if (b >= 32) return;
        int lo = 0, hi = N, v0 = b << 9;
        while (lo < hi) { int mid = (lo + hi) >> 1; if (idx[mid] < v0) lo = mid + 1; else hi = mid; }
        int s = lo;
        lo = 0; hi = N; int v1 = (b + 1) << 9;
        while (lo < hi) { int mid = (lo + hi) >> 1; if (idx[mid] < v1) lo = mid + 1; else hi = mid; }
        bcnt[b] = lo - s;
        return;
    }
    if (gid >= 656128) {
        int j = gid - 656128;
        int i = j >> 5;
        if (i >= N) return;
        int c8 = (j & 31) * 8;
        const float* sp = x + (size_t)i * Cc + c8;
        float4 f0 = *(const float4*)sp;
        float4 f1 = *(const float4*)(sp + 4);
        us8_t pk;
        pk[0] = f2bf_fast(f0.x); pk[1] = f2bf_fast(f0.y);
        pk[2] = f2bf_fast(f0.z); pk[3] = f2bf_fast(f0.w);
        pk[4] = f2bf_fast(f1.x); pk[5] = f2bf_fast(f1.y);
        pk[6] = f2bf_fast(f1.z); pk[7] = f2bf_fast(f1.w);
        *(us8_t*)&x_bf[(size_t)i * Cc + c8] = pk;
        int slot = idx[i];
        *(us8_t*)&xd_bf[(size_t)slot * Cc + c8] = pk;
        return;
    }
    if (gid >= 655360) {
        int j = gid - 655360;
        bqkv[j] = (j < 256) ? bq[j] * scale : (j < 512 ? bk[j - 256] : bv[j - 512]);
        return;
    }
    const float* src; int base, K, N_; float mul = 1.f;
    if (gid < 65536)       { src = Wr; base = 0;      K = 256; N_ = 256; }
    else if (gid < 131072) { src = Wn; base = 65536;  K = 256; N_ = 256; }
    else if (gid < 196608) { src = Wq; base = 131072; K = 256; N_ = 256; mul = scale; }
    else if (gid < 262144) { src = Wk; base = 196608; K = 256; N_ = 256; }
    else if (gid < 327680) { src = Wv; base = 262144; K = 256; N_ = 256; }
    else if (gid < 393216) { src = Wo; base = 327680; K = 256; N_ = 256; }
    else if (gid < 524288) { src = W1; base = 393216; K = 256; N_ = 512; }
    else                   { src = W2; base = 524288; K = 512; N_ = 256; }
    int loc = gid - base;
    int n = loc / K, k = loc % K;
    wsq[gid] = f2bf(src[(size_t)k * N_ + n] * mul);
}

// ---------------------------------------------------------------------------
// Direct fixed-stride CSR fill + gather (unchanged from R14)
// ---------------------------------------------------------------------------
__global__ void fill_csr_kernel(const int* __restrict__ ei, int* __restrict__ cursor,
                                int* __restrict__ csr, int E) {
    int e = blockIdx.x * 256 + threadIdx.x;
    if (e >= E) return;
    int dst = ei[E + e];
    int pos = atomicAdd(&cursor[dst], 1);
    if (pos < CSTRIDE) csr[(size_t)dst * CSTRIDE + pos] = ei[e];
}

__global__ __launch_bounds__(256) void gather_kernel(const unsigned short* __restrict__ x_bf,
                                                     const int* __restrict__ csr,
                                                     const int* __restrict__ cursor,
                                                     unsigned short* __restrict__ agg_bf,
                                                     int N) {
    int i = blockIdx.x * 4 + (threadIdx.x >> 6);
    if (i >= N) return;
    int l4 = (threadIdx.x & 63) * 4;
    int dcount = cursor[i];
    if (dcount > CSTRIDE) dcount = CSTRIDE;
    const int* row = csr + (size_t)i * CSTRIDE;
    f32x4 a0 = {0.f, 0.f, 0.f, 0.f}, a1 = a0, a2 = a0, a3 = a0;
    int e = 0;
    for (; e + 4 <= dcount; e += 4) {
        int i0 = row[e + 0];
        int i1 = row[e + 1];
        int i2 = row[e + 2];
        int i3 = row[e + 3];
        ushort4 u0 = *(const ushort4*)(x_bf + (size_t)i0 * Cc + l4);
        ushort4 u1 = *(const ushort4*)(x_bf + (size_t)i1 * Cc + l4);
        ushort4 u2 = *(const ushort4*)(x_bf + (size_t)i2 * Cc + l4);
        ushort4 u3 = *(const ushort4*)(x_bf + (size_t)i3 * Cc + l4);
        a0[0] += bf2f(u0.x); a0[1] += bf2f(u0.y); a0[2] += bf2f(u0.z); a0[3] += bf2f(u0.w);
        a1[0] += bf2f(u1.x); a1[1] += bf2f(u1.y); a1[2] += bf2f(u1.z); a1[3] += bf2f(u1.w);
        a2[0] += bf2f(u2.x); a2[1] += bf2f(u2.y); a2[2] += bf2f(u2.z); a2[3] += bf2f(u2.w);
        a3[0] += bf2f(u3.x); a3[1] += bf2f(u3.y); a3[2] += bf2f(u3.z); a3[3] += bf2f(u3.w);
    }
    for (; e < dcount; ++e) {
        ushort4 u = *(const ushort4*)(x_bf + (size_t)row[e] * Cc + l4);
        a0[0] += bf2f(u.x); a0[1] += bf2f(u.y); a0[2] += bf2f(u.z); a0[3] += bf2f(u.w);
    }
    f32x4 s = (a0 + a1) + (a2 + a3);
    ushort4 w4;
    w4.x = f2bf_fast(s[0]); w4.y = f2bf_fast(s[1]);
    w4.z = f2bf_fast(s[2]); w4.w = f2bf_fast(s[3]);
    *(ushort4*)&agg_bf[(size_t)i * Cc + l4] = w4;
}

// ---------------------------------------------------------------------------
// GEMM body: 128x128 tile, BK=32, 4 waves each 64x64 output.
// LDS rows = 32 ushorts (64B), XOR chunk swizzle (chunk ^= row&3): 2-way banks.
// Register prefetch of next K-tile hides global latency under 16 MFMAs.
// ---------------------------------------------------------------------------
template <bool RELU, bool OUTBF16, bool STATS>
__device__ __forceinline__ void gemm_body(
    const unsigned short* __restrict__ A, const int* __restrict__ gidx,
    const unsigned short* __restrict__ Bt,
    const unsigned short* __restrict__ A2, const unsigned short* __restrict__ B2t,
    const float* __restrict__ bias, const float* __restrict__ res,
    void* __restrict__ Cout, float* __restrict__ stats, int M, int K, int Nc,
    int bx, int by, unsigned short* As, unsigned short* Bs) {
    int tid = threadIdx.x;
    int row0 = by * 128;
    int col0 = bx * 128;
    int lane = tid & 63;
    int w = tid >> 6;
    int wr = (w >> 1) * 64;
    int wc = (w & 1) * 64;
    int fr = lane & 15;
    int g = lane >> 4;

    f32x4 acc[4][4] = {};

    // staging: 128 rows x 32 k, 2 us8 chunks per thread (chunks c0, c0+1)
    int r = tid >> 1;              // 0..127
    int c0 = (tid & 1) * 2;        // 0 or 2
    int kc = c0 * 8;               // ushort offset in row: 0 or 16
    int so0 = r * LDSW + ((c0 ^ (r & 3)) << 3);
    int so1 = r * LDSW + (((c0 + 1) ^ (r & 3)) << 3);

    int npass = (A2 != nullptr) ? 2 : 1;
    for (int pass = 0; pass < npass; ++pass) {
        const unsigned short* Ap = pass ? A2 : A;
        const unsigned short* Bp = pass ? B2t : Bt;
        int ar = row0 + r;
        if (ar >= M) ar = M - 1;   // clamp: finite garbage, store-guarded
        int arr = gidx ? gidx[ar] : ar;
        const unsigned short* abase = Ap + (size_t)arr * K + kc;
        const unsigned short* bbase = Bp + (size_t)(col0 + r) * K + kc;
        us8_t pa0 = *(const us8_t*)(abase);
        us8_t pa1 = *(const us8_t*)(abase + 8);
        us8_t pb0 = *(const us8_t*)(bbase);
        us8_t pb1 = *(const us8_t*)(bbase + 8);
        for (int k0 = 0; k0 < K; k0 += 32) {
            __syncthreads();
            *(us8_t*)&As[so0] = pa0;
            *(us8_t*)&As[so1] = pa1;
            *(us8_t*)&Bs[so0] = pb0;
            *(us8_t*)&Bs[so1] = pb1;
            __syncthreads();
            int k1 = k0 + 32;
            if (k1 < K) {          // prefetch next tile (overlaps with MFMAs)
                pa0 = *(const us8_t*)(abase + k1);
                pa1 = *(const us8_t*)(abase + k1 + 8);
                pb0 = *(const us8_t*)(bbase + k1);
                pb1 = *(const us8_t*)(bbase + k1 + 8);
            }
            bf16x8 bfr[4];
#pragma unroll
            for (int fn = 0; fn < 4; ++fn) {
                int br = wc + fn * 16 + fr;
                bfr[fn] = *(bf16x8*)&Bs[br * LDSW + ((g ^ (br & 3)) << 3)];
            }
#pragma unroll
            for (int fm = 0; fm < 4; ++fm) {
                int arow = wr + fm * 16 + fr;
                bf16x8 af = *(bf16x8*)&As[arow * LDSW + ((g ^ (arow & 3)) << 3)];
#pragma unroll
                for (int fn = 0; fn < 4; ++fn)
                    acc[fm][fn] =
                        __builtin_amdgcn_mfma_f32_16x16x32_bf16(af, bfr[fn], acc[fm][fn], 0, 0, 0);
            }
        }
    }
    int rq = g * 4;
    float cs[4] = {0.f, 0.f, 0.f, 0.f}, cq[4] = {0.f, 0.f, 0.f, 0.f};
#pragma unroll
    for (int fm = 0; fm < 4; ++fm) {
#pragma unroll
        for (int fn = 0; fn < 4; ++fn) {
            int col = col0 + wc + fn * 16 + fr;
#pragma unroll
            for (int i = 0; i < 4; ++i) {
                int row = row0 + wr + fm * 16 + rq + i;
                if (row < M) {
                    float v = acc[fm][fn][i];
                    if (bias) v += bias[col];
                    if (res) v += res[(size_t)row * Nc + col];
                    if (RELU) v = fmaxf(v, 0.f);
                    if (OUTBF16)
                        ((unsigned short*)Cout)[(size_t)row * Nc + col] = f2bf_fast(v);
                    else
                        ((float*)Cout)[(size_t)row * Nc + col] = v;
                    if (STATS) { cs[fn] += v; cq[fn] += v * v; }
                }
            }
        }
    }
    if (STATS) {
#pragma unroll
        for (int fn = 0; fn < 4; ++fn) {
            cs[fn] += __shfl_xor(cs[fn], 16); cs[fn] += __shfl_xor(cs[fn], 32);
            cq[fn] += __shfl_xor(cq[fn], 16); cq[fn] += __shfl_xor(cq[fn], 32);
        }
        if (g == 0) {
#pragma unroll
            for (int fn = 0; fn < 4; ++fn) {
                int col = col0 + wc + fn * 16 + fr;
                atomicAdd(&stats[col], cs[fn]);
                atomicAdd(&stats[256 + col], cq[fn]);
            }
        }
    }
}

// Wrapper for standalone GEMMs
template <bool RELU, bool OUTBF16, bool STATS>
__global__ __launch_bounds__(256) void gemm_mfma_kernel(
    const unsigned short* A, const int* gidx, const unsigned short* Bt,
    const unsigned short* A2, const unsigned short* B2t,
    const float* bias, const float* res, void* Cout, float* stats,
    int M, int K, int Nc) {
    __shared__ unsigned short As[128 * LDSW];
    __shared__ unsigned short Bs[128 * LDSW];
    gemm_body<RELU, OUTBF16, STATS>(A, gidx, Bt, A2, B2t, bias, res, Cout, stats,
                                    M, K, Nc, blockIdx.x, blockIdx.y, As, Bs);
}

// Combined conv+QKV dispatch
__global__ __launch_bounds__(256) void convqkv_kernel(
    const unsigned short* __restrict__ x_bf, const unsigned short* __restrict__ agg_bf,
    const unsigned short* __restrict__ Wrt, const unsigned short* __restrict__ Wnt,
    const unsigned short* __restrict__ Wqkvt,
    const float* __restrict__ b_conv, const float* __restrict__ x,
    float* __restrict__ hB, float* __restrict__ stats,
    const unsigned short* __restrict__ xd_bf, const float* __restrict__ bqkv,
    unsigned short* __restrict__ qkvb, int N, int convBlocks) {
    __shared__ unsigned short As[128 * LDSW];
    __shared__ unsigned short Bs[128 * LDSW];
    int blk = blockIdx.x;
    if (blk < convBlocks) {
        gemm_body<false, false, true>(x_bf, nullptr, Wrt, agg_bf, Wnt, b_conv, x,
                                      hB, stats, N, 256, 256, blk & 1, blk >> 1, As, Bs);
    } else {
        int q = blk - convBlocks;
        gemm_body<false, true, false>(xd_bf, nullptr, Wqkvt, nullptr, nullptr, bqkv, nullptr,
                                      qkvb, nullptr, BT, 256, 768, q % 6, q / 6, As, Bs);
    }
}

// ---------------------------------------------------------------------------
// BN applies (unchanged)
// ---------------------------------------------------------------------------
__global__ void bn_apply_kernel(const float* __restrict__ in, float* __restrict__ out,
                                const float* __restrict__ g, const float* __restrict__ be,
                                const float* __restrict__ stats, int M) {
    int gid = blockIdx.x * 256 + threadIdx.x;
    if (gid >= M * Cc) return;
    int c = gid & (Cc - 1);
    float invM = 1.f / (float)M;
    float mean = stats[c] * invM;
    float var = stats[Cc + c] * invM - mean * mean;
    float sc = g[c] * rsqrtf(var + EPS);
    out[gid] = (in[gid] - mean) * sc + be[c];
}

__global__ void bn12_apply_kernel(const float* __restrict__ hpre,
                                  const float* __restrict__ hattn,
                                  const float* __restrict__ g1, const float* __restrict__ be1,
                                  const float* __restrict__ g2, const float* __restrict__ be2,
                                  const float* __restrict__ stats,
                                  float* __restrict__ out, unsigned short* __restrict__ out_bf,
                                  int M) {
    int gid = blockIdx.x * 256 + threadIdx.x;
    if (gid >= M * Cc) return;
    int c = gid & (Cc - 1);
    float invM = 1.f / (float)M;
    float mean1 = stats[c] * invM;
    float var1 = stats[Cc + c] * invM - mean1 * mean1;
    float sc1 = g1[c] * rsqrtf(var1 + EPS);
    float mean2 = stats[2 * Cc + c] * invM;
    float var2 = stats[3 * Cc + c] * invM - mean2 * mean2;
    float sc2 = g2[c] * rsqrtf(var2 + EPS);
    float v = (hpre[gid] - mean1) * sc1 + be1[c] + (hattn[gid] - mean2) * sc2 + be2[c];
    out[gid] = v;
    out_bf[gid] = f2bf_fast(v);
}

// ---------------------------------------------------------------------------
// MFMA flash attention (unchanged from R14)
// ---------------------------------------------------------------------------
__global__ __launch_bounds__(256) void attn_mfma_kernel(const unsigned short* __restrict__ qkvb,
                                                        const int* __restrict__ bcnt,
                                                        unsigned short* __restrict__ o_bf) {
    const int blk = ((blockIdx.x & 7) << 7) | ((int)blockIdx.x >> 3);  // XCD swizzle (1024 wgs)
    const int qt = blk & 3;
    const int bh = blk >> 2;
    const int b = bh >> 3;
    const int h = bh & 7;
    const int tid = threadIdx.x;
    const int lane = tid & 63;
    const int w = tid >> 6;
    const int fr = lane & 15;
    const int g = lane >> 4;
    const int kk = g * 8;
    const int q0 = qt * 128 + w * 32;

    __shared__ unsigned short Ks[32 * LDAP];
    __shared__ unsigned short Vt[32 * LDAP];
    __shared__ unsigned short Pl[4][2][16 * LDAP];

    const int count = bcnt[b];

    const unsigned short* qp = qkvb + (size_t)(b * Tc + q0 + fr) * 768 + h * 32 + kk;
    bf16x8 qa0 = *(const bf16x8*)qp;
    bf16x8 qa1 = *(const bf16x8*)(qp + (size_t)16 * 768);

    f32x4 op00 = {0.f, 0.f, 0.f, 0.f}, op01 = op00;
    f32x4 op10 = op00, op11 = op00;
    float l0 = 0.f, l1 = 0.f;
    float m0 = -1e30f, m1 = -1e30f;

    const int nt = (count + 31) >> 5;
    for (int t = 0; t < nt; ++t) {
        const int kbase = t * 32;
        __syncthreads();
        {
            int key = tid >> 3;
            int d4 = (tid & 7) * 4;
            const unsigned short* kp =
                qkvb + (size_t)(b * Tc + kbase + key) * 768 + 256 + h * 32 + d4;
            *(ushort4*)&Ks[key * LDAP + d4] = *(const ushort4*)kp;
        }
        {
            int vkey = tid & 31;
            int d0 = (tid >> 5) * 4;
            const unsigned short* vp =
                qkvb + (size_t)(b * Tc + kbase + vkey) * 768 + 512 + h * 32 + d0;
            ushort4 vv = *(const ushort4*)vp;
            Vt[(d0 + 0) * LDAP + vkey] = vv.x;
            Vt[(d0 + 1) * LDAP + vkey] = vv.y;
            Vt[(d0 + 2) * LDAP + vkey] = vv.z;
            Vt[(d0 + 3) * LDAP + vkey] = vv.w;
        }
        __syncthreads();

        bf16x8 ka0 = *(bf16x8*)&Ks[fr * LDAP + kk];
        bf16x8 ka1 = *(bf16x8*)&Ks[(16 + fr) * LDAP + kk];
        f32x4 z = {0.f, 0.f, 0.f, 0.f};
        f32x4 s00 = __builtin_amdgcn_mfma_f32_16x16x32_bf16(ka0, qa0, z, 0, 0, 0);
        f32x4 s10 = __builtin_amdgcn_mfma_f32_16x16x32_bf16(ka1, qa0, z, 0, 0, 0);
        f32x4 s01 = __builtin_amdgcn_mfma_f32_16x16x32_bf16(ka0, qa1, z, 0, 0, 0);
        f32x4 s11 = __builtin_amdgcn_mfma_f32_16x16x32_bf16(ka1, qa1, z, 0, 0, 0);

#pragma unroll
        for (int i = 0; i < 4; ++i) {
            bool v0 = (kbase + g * 4 + i) < count;
            bool v1 = (kbase + 16 + g * 4 + i) < count;
            s00[i] = v0 ? s00[i] : -1e30f;
            s01[i] = v0 ? s01[i] : -1e30f;
            s10[i] = v1 ? s10[i] : -1e30f;
            s11[i] = v1 ? s11[i] : -1e30f;
        }

        float r0_ = fmaxf(fmaxf(fmaxf(s00[0], s00[1]), fmaxf(s00[2], s00[3])),
                          fmaxf(fmaxf(s10[0], s10[1]), fmaxf(s10[2], s10[3])));
        r0_ = fmaxf(r0_, __shfl_xor(r0_, 16));
        r0_ = fmaxf(r0_, __shfl_xor(r0_, 32));
        float mn0 = fmaxf(m0, r0_);
        float c0 = __expf(m0 - mn0);
        m0 = mn0;
        l0 *= c0;
        float p00[4], p10[4];
#pragma unroll
        for (int i = 0; i < 4; ++i) {
            p00[i] = __expf(s00[i] - mn0);
            p10[i] = __expf(s10[i] - mn0);
            l0 += p00[i] + p10[i];
        }
        float r1_ = fmaxf(fmaxf(fmaxf(s01[0], s01[1]), fmaxf(s01[2], s01[3])),
                          fmaxf(fmaxf(s11[0], s11[1]), fmaxf(s11[2], s11[3])));
        r1_ = fmaxf(r1_, __shfl_xor(r1_, 16));
        r1_ = fmaxf(r1_, __shfl_xor(r1_, 32));
        float mn1 = fmaxf(m1, r1_);
        float c1 = __expf(m1 - mn1);
        m1 = mn1;
        l1 *= c1;
        float p01[4], p11[4];
#pragma unroll
        for (int i = 0; i < 4; ++i) {
            p01[i] = __expf(s01[i] - mn1);
            p11[i] = __expf(s11[i] - mn1);
            l1 += p01[i] + p11[i];
        }

        unsigned short* pw0 = &Pl[w][0][0];
        unsigned short* pw1 = &Pl[w][1][0];
        ushort4 q00, q10, q01, q11;
        q00.x = f2bf_fast(p00[0]); q00.y = f2bf_fast(p00[1]);
        q00.z = f2bf_fast(p00[2]); q00.w = f2bf_fast(p00[3]);
        q10.x = f2bf_fast(p10[0]); q10.y = f2bf_fast(p10[1]);
        q10.z = f2bf_fast(p10[2]); q10.w = f2bf_fast(p10[3]);
        q01.x = f2bf_fast(p01[0]); q01.y = f2bf_fast(p01[1]);
        q01.z = f2bf_fast(p01[2]); q01.w = f2bf_fast(p01[3]);
        q11.x = f2bf_fast(p11[0]); q11.y = f2bf_fast(p11[1]);
        q11.z = f2bf_fast(p11[2]); q11.w = f2bf_fast(p11[3]);
        *(ushort4*)&pw0[fr * LDAP + g * 4] = q00;
        *(ushort4*)&pw0[fr * LDAP + 16 + g * 4] = q10;
        *(ushort4*)&pw1[fr * LDAP + g * 4] = q01;
        *(ushort4*)&pw1[fr * LDAP + 16 + g * 4] = q11;

#pragma unroll
        for (int i = 0; i < 4; ++i) {
            float ci0 = __shfl(c0, g * 4 + i);
            float ci1 = __shfl(c1, g * 4 + i);
            op00[i] *= ci0; op01[i] *= ci0;
            op10[i] *= ci1; op11[i] *= ci1;
        }

        asm volatile("s_waitcnt lgkmcnt(0)" ::: "memory");
        __builtin_amdgcn_sched_barrier(0);

        bf16x8 pa0 = *(bf16x8*)&pw0[fr * LDAP + kk];
        bf16x8 pa1 = *(bf16x8*)&pw1[fr * LDAP + kk];
        bf16x8 vb0 = *(bf16x8*)&Vt[fr * LDAP + kk];
        bf16x8 vb1 = *(bf16x8*)&Vt[(16 + fr) * LDAP + kk];
        op00 = __builtin_amdgcn_mfma_f32_16x16x32_bf16(pa0, vb0, op00, 0, 0, 0);
        op01 = __builtin_amdgcn_mfma_f32_16x16x32_bf16(pa0, vb1, op01, 0, 0, 0);
        op10 = __builtin_amdgcn_mfma_f32_16x16x32_bf16(pa1, vb0, op10, 0, 0, 0);
        op11 = __builtin_amdgcn_mfma_f32_16x16x32_bf16(pa1, vb1, op11, 0, 0, 0);
    }

    l0 += __shfl_xor(l0, 16); l0 += __shfl_xor(l0, 32);
    l1 += __shfl_xor(l1, 16); l1 += __shfl_xor(l1, 32);
    float inv0 = 1.f / l0;
    float inv1 = 1.f / l1;
#pragma unroll
    for (int i = 0; i < 4; ++i) {
        float li0 = __shfl(inv0, g * 4 + i);
        float li1 = __shfl(inv1, g * 4 + i);
        size_t row0 = (size_t)(b * Tc + q0 + g * 4 + i);
        size_t row1 = row0 + 16;
        o_bf[row0 * Cc + h * 32 + fr] = f2bf_fast(op00[i] * li0);
        o_bf[row0 * Cc + h * 32 + 16 + fr] = f2bf_fast(op01[i] * li0);
        o_bf[row1 * Cc + h * 32 + fr] = f2bf_fast(op10[i] * li1);
        o_bf[row1 * Cc + h * 32 + 16 + fr] = f2bf_fast(op11[i] * li1);
    }
}

// ---------------------------------------------------------------------------
// Launch (10 dispatches)
// ---------------------------------------------------------------------------
extern "C" void kernel_launch(void* const* d_in, const int* in_sizes, int n_in,
                              void* d_out, int out_size, void* d_ws, size_t ws_size,
                              hipStream_t stream) {
    const float* x      = (const float*)d_in[0];
    const int*   ei     = (const int*)d_in[1];
    const int*   idx    = (const int*)d_in[2];
    const float* W_root = (const float*)d_in[4];
    const float* W_nbr  = (const float*)d_in[5];
    const float* b_conv = (const float*)d_in[6];
    const float* Wq     = (const float*)d_in[7];
    const float* Wk     = (const float*)d_in[8];
    const float* Wv     = (const float*)d_in[9];
    const float* bq     = (const float*)d_in[10];
    const float* bk     = (const float*)d_in[11];
    const float* bv     = (const float*)d_in[12];
    const float* Wo     = (const float*)d_in[13];
    const float* bo     = (const float*)d_in[14];
    const float* W1     = (const float*)d_in[15];
    const float* b1     = (const float*)d_in[16];
    const float* W2     = (const float*)d_in[17];
    const float* b2     = (const float*)d_in[18];
    const float* g1     = (const float*)d_in[19];
    const float* be1    = (const float*)d_in[20];
    const float* g2     = (const float*)d_in[21];
    const float* be2    = (const float*)d_in[22];
    const float* g3     = (const float*)d_in[23];
    const float* be3    = (const float*)d_in[24];

    const int N = in_sizes[0] / Cc;
    const int E = in_sizes[1] / 2;

    // Workspace layout
    float* ws = (float*)d_ws;
    float* hB    = ws;                                       // N*C f32 (h_pre -> out1)
    float* bqkv  = hB + (size_t)N * Cc;                      // 768
    unsigned short* wsq    = (unsigned short*)(bqkv + 768);  // 655360
    unsigned short* x_bf   = wsq + 655360;                   // N*C
    unsigned short* hB_bf  = x_bf + (size_t)N * Cc;          // N*C
    unsigned short* hid_bf = hB_bf + (size_t)N * Cc;         // N*2C
    unsigned short* xd_bf  = hid_bf + (size_t)N * 2 * Cc;    // BT*C (also attn out)
    unsigned short* qkvb   = xd_bf + (size_t)BT * Cc;        // BT*768
    int*   bcnt   = (int*)(qkvb + (size_t)BT * 768);         // 32
    float* stats  = (float*)(bcnt + 32);                     // 6*C, start of zeroed region
    int*   cursor = (int*)(stats + 6 * Cc);                  // N (degree counters), zeroed
    int*   csr    = cursor + N;                              // N*CSTRIDE
    float* bufA   = (float*)d_out;                           // N*C scratch
    unsigned short* agg_bf = (unsigned short*)d_out;
    unsigned short* ao = xd_bf;

    const unsigned short* Wrt   = wsq;
    const unsigned short* Wnt   = wsq + 65536;
    const unsigned short* Wqkvt = wsq + 131072;
    const unsigned short* Wot   = wsq + 327680;
    const unsigned short* W1t   = wsq + 393216;
    const unsigned short* W2t   = wsq + 524288;

    const int nzero = 6 * Cc + N;          // stats floats + cursor ints (contiguous)
    const int nzero4 = (nzero + 3) / 4;

    // 1: mega-fused prologue
    {
        int total = 656128 + N * 32 + 64 + nzero4;
        wcvt_fused_kernel<<<(total + 255) / 256, 256, 0, stream>>>(
            W_root, W_nbr, Wq, Wk, Wv, Wo, W1, W2, bq, bk, bv, wsq, bqkv,
            x, idx, x_bf, xd_bf, bcnt, (int*)stats, N, nzero4);
    }

    // 2: direct CSR fill (cursor -> degree)
    fill_csr_kernel<<<(E + 255) / 256, 256, 0, stream>>>(ei, cursor, csr, E);

    // 3: gather (agg -> bf16 in d_out region)
    gather_kernel<<<(N + 3) / 4, 256, 0, stream>>>(x_bf, csr, cursor, agg_bf, N);

    // 4: combined conv GEMM (+BN1 stats) and QKV GEMM (->bf16), 128x128 tiles
    {
        int convBlocks = 2 * ((N + 127) / 128);
        int qkvBlocks = 6 * (BT / 128);
        convqkv_kernel<<<convBlocks + qkvBlocks, 256, 0, stream>>>(
            x_bf, agg_bf, Wrt, Wnt, Wqkvt, b_conv, x, hB, stats,
            xd_bf, bqkv, qkvb, N, convBlocks);
    }

    // 5: attention
    attn_mfma_kernel<<<Bc * Hc * 4, 256, 0, stream>>>(qkvb, bcnt, ao);

    // 6: Wo GEMM + BN2 stats
    {
        dim3 grid(Cc / 128, (N + 127) / 128);
        gemm_mfma_kernel<false, false, true><<<grid, 256, 0, stream>>>(
            ao, idx, Wot, nullptr, nullptr, bo, x, bufA, stats + 2 * Cc, N, Cc, Cc);
    }

    // 7: fused BN1+BN2 apply -> out1 (f32 hB + bf16 hB_bf)
    bn12_apply_kernel<<<(N * Cc + 255) / 256, 256, 0, stream>>>(
        hB, bufA, g1, be1, g2, be2, stats, hB, hB_bf, N);

    // 8: W1 GEMM (relu) -> bf16 hid
    {
        dim3 grid(512 / 128, (N + 127) / 128);
        gemm_mfma_kernel<true, true, false><<<grid, 256, 0, stream>>>(
            hB_bf, nullptr, W1t, nullptr, nullptr, b1, nullptr, hid_bf, nullptr, N, Cc, 512);
    }

    // 9: W2 GEMM + BN3 stats
    {
        dim3 grid(Cc / 128, (N + 127) / 128);
        gemm_mfma_kernel<false, false, true><<<grid, 256, 0, stream>>>(
            hid_bf, nullptr, W2t, nullptr, nullptr, b2, hB, bufA, stats + 4 * Cc, N, 512, Cc);
    }

    // 10: BN3 apply in place on d_out
    bn_apply_kernel<<<(N * Cc + 255) / 256, 256, 0, stream>>>(
        bufA, bufA, g3, be3, stats + 4 * Cc, N);
}

// Round 16
// 230.561 us; speedup vs baseline: 1.1235x; 1.1235x over previous
//
#include <hip/hip_runtime.h>
#include <hip/hip_bf16.h>
#include <math.h>

#define Bc 32
#define Tc 512
#define Cc 256
#define Hc 8
#define BT (Bc * Tc)
#define EPS 1e-5f
#define LDAP 40      // LDS row stride (ushorts, 80B): slot=(5*row+chunk)%8, gcd(5,8)=1
#define CSTRIDE 128  // fixed CSR row stride

typedef __bf16 bf16x8 __attribute__((ext_vector_type(8)));
typedef float f32x4 __attribute__((ext_vector_type(4)));
typedef unsigned short us8_t __attribute__((ext_vector_type(8)));

__device__ inline unsigned short f2bf(float f) {
    unsigned int u = __float_as_uint(f);
    u += 0x7fffu + ((u >> 16) & 1u);
    return (unsigned short)(u >> 16);
}
__device__ inline unsigned short f2bf_fast(float f) {
    __bf16 h = (__bf16)f;
    return __builtin_bit_cast(unsigned short, h);
}
__device__ inline float bf2f(unsigned short u) {
    return __uint_as_float((unsigned int)u << 16);
}

// ---------------------------------------------------------------------------
// Mega-fused prologue (unchanged from R14)
// ---------------------------------------------------------------------------
__global__ void wcvt_fused_kernel(const float* __restrict__ Wr, const float* __restrict__ Wn,
                                  const float* __restrict__ Wq, const float* __restrict__ Wk,
                                  const float* __restrict__ Wv, const float* __restrict__ Wo,
                                  const float* __restrict__ W1, const float* __restrict__ W2,
                                  const float* __restrict__ bq, const float* __restrict__ bk,
                                  const float* __restrict__ bv,
                                  unsigned short* __restrict__ wsq, float* __restrict__ bqkv,
                                  const float* __restrict__ x, const int* __restrict__ idx,
                                  unsigned short* __restrict__ x_bf,
                                  unsigned short* __restrict__ xd_bf,
                                  int* __restrict__ bcnt, int* __restrict__ zbase,
                                  int N, int nzero4) {
    const float scale = 0.17677669529663687f;  // 1/sqrt(32)
    int gid = blockIdx.x * 256 + threadIdx.x;
    const int X0 = 656128 + N * 32;
    const int XZ = X0 + 64;
    if (gid >= XZ) {
        int j = gid - XZ;
        if (j < nzero4) {
            int4 z = {0, 0, 0, 0};
            *(int4*)&zbase[j * 4] = z;
        }
        return;
    }
    if (gid >= X0) {
        int b = gid - X0;
        if (b >= 32) return;
        int lo = 0, hi = N, v0 = b << 9;
        while (lo < hi) { int mid = (lo + hi) >> 1; if (idx[mid] < v0) lo = mid + 1; else hi = mid; }
        int s = lo;
        lo = 0; hi = N; int v1 = (b + 1) << 9;
        while (lo < hi) { int mid = (lo + hi) >> 1; if (idx[mid] < v1) lo = mid + 1; else hi = mid; }
        bcnt[b] = lo - s;
        return;
    }
    if (gid >= 656128) {
        int j = gid - 656128;
        int i = j >> 5;
        if (i >= N) return;
        int c8 = (j & 31) * 8;
        const float* sp = x + (size_t)i * Cc + c8;
        float4 f0 = *(const float4*)sp;
        float4 f1 = *(const float4*)(sp + 4);
        us8_t pk;
        pk[0] = f2bf_fast(f0.x); pk[1] = f2bf_fast(f0.y);
        pk[2] = f2bf_fast(f0.z); pk[3] = f2bf_fast(f0.w);
        pk[4] = f2bf_fast(f1.x); pk[5] = f2bf_fast(f1.y);
        pk[6] = f2bf_fast(f1.z); pk[7] = f2bf_fast(f1.w);
        *(us8_t*)&x_bf[(size_t)i * Cc + c8] = pk;
        int slot = idx[i];
        *(us8_t*)&xd_bf[(size_t)slot * Cc + c8] = pk;
        return;
    }
    if (gid >= 655360) {
        int j = gid - 655360;
        bqkv[j] = (j < 256) ? bq[j] * scale : (j < 512 ? bk[j - 256] : bv[j - 512]);
        return;
    }
    const float* src; int base, K, N_; float mul = 1.f;
    if (gid < 65536)       { src = Wr; base = 0;      K = 256; N_ = 256; }
    else if (gid < 131072) { src = Wn; base = 65536;  K = 256; N_ = 256; }
    else if (gid < 196608) { src = Wq; base = 131072; K = 256; N_ = 256; mul = scale; }
    else if (gid < 262144) { src = Wk; base = 196608; K = 256; N_ = 256; }
    else if (gid < 327680) { src = Wv; base = 262144; K = 256; N_ = 256; }
    else if (gid < 393216) { src = Wo; base = 327680; K = 256; N_ = 256; }
    else if (gid < 524288) { src = W1; base = 393216; K = 256; N_ = 512; }
    else                   { src = W2; base = 524288; K = 512; N_ = 256; }
    int loc = gid - base;
    int n = loc / K, k = loc % K;
    wsq[gid] = f2bf(src[(size_t)k * N_ + n] * mul);
}

// ---------------------------------------------------------------------------
// Direct fixed-stride CSR fill + gather (unchanged from R14)
// ---------------------------------------------------------------------------
__global__ void fill_csr_kernel(const int* __restrict__ ei, int* __restrict__ cursor,
                                int* __restrict__ csr, int E) {
    int e = blockIdx.x * 256 + threadIdx.x;
    if (e >= E) return;
    int dst = ei[E + e];
    int pos = atomicAdd(&cursor[dst], 1);
    if (pos < CSTRIDE) csr[(size_t)dst * CSTRIDE + pos] = ei[e];
}

__global__ __launch_bounds__(256) void gather_kernel(const unsigned short* __restrict__ x_bf,
                                                     const int* __restrict__ csr,
                                                     const int* __restrict__ cursor,
                                                     unsigned short* __restrict__ agg_bf,
                                                     int N) {
    int i = blockIdx.x * 4 + (threadIdx.x >> 6);
    if (i >= N) return;
    int l4 = (threadIdx.x & 63) * 4;
    int dcount = cursor[i];
    if (dcount > CSTRIDE) dcount = CSTRIDE;
    const int* row = csr + (size_t)i * CSTRIDE;
    f32x4 a0 = {0.f, 0.f, 0.f, 0.f}, a1 = a0, a2 = a0, a3 = a0;
    int e = 0;
    for (; e + 4 <= dcount; e += 4) {
        int i0 = row[e + 0];
        int i1 = row[e + 1];
        int i2 = row[e + 2];
        int i3 = row[e + 3];
        ushort4 u0 = *(const ushort4*)(x_bf + (size_t)i0 * Cc + l4);
        ushort4 u1 = *(const ushort4*)(x_bf + (size_t)i1 * Cc + l4);
        ushort4 u2 = *(const ushort4*)(x_bf + (size_t)i2 * Cc + l4);
        ushort4 u3 = *(const ushort4*)(x_bf + (size_t)i3 * Cc + l4);
        a0[0] += bf2f(u0.x); a0[1] += bf2f(u0.y); a0[2] += bf2f(u0.z); a0[3] += bf2f(u0.w);
        a1[0] += bf2f(u1.x); a1[1] += bf2f(u1.y); a1[2] += bf2f(u1.z); a1[3] += bf2f(u1.w);
        a2[0] += bf2f(u2.x); a2[1] += bf2f(u2.y); a2[2] += bf2f(u2.z); a2[3] += bf2f(u2.w);
        a3[0] += bf2f(u3.x); a3[1] += bf2f(u3.y); a3[2] += bf2f(u3.z); a3[3] += bf2f(u3.w);
    }
    for (; e < dcount; ++e) {
        ushort4 u = *(const ushort4*)(x_bf + (size_t)row[e] * Cc + l4);
        a0[0] += bf2f(u.x); a0[1] += bf2f(u.y); a0[2] += bf2f(u.z); a0[3] += bf2f(u.w);
    }
    f32x4 s = (a0 + a1) + (a2 + a3);
    ushort4 w4;
    w4.x = f2bf_fast(s[0]); w4.y = f2bf_fast(s[1]);
    w4.z = f2bf_fast(s[2]); w4.w = f2bf_fast(s[3]);
    *(ushort4*)&agg_bf[(size_t)i * Cc + l4] = w4;
}

// ---------------------------------------------------------------------------
// GEMM body (R14 core): 128x64 tile, BK=32, 4 waves each owning 64x32.
// Change vs R14: B-staging remapped to bc=tid&63, bkc=(tid>>6)*8 so wave w
// writes chunk w of rows 0..63 -> bank slot (5l+w)%8, perfectly balanced.
// ---------------------------------------------------------------------------
template <bool RELU, bool OUTBF16, bool STATS>
__device__ __forceinline__ void gemm_body(
    const unsigned short* __restrict__ A, const int* __restrict__ gidx,
    const unsigned short* __restrict__ Bt,
    const unsigned short* __restrict__ A2, const unsigned short* __restrict__ B2t,
    const float* __restrict__ bias, const float* __restrict__ res,
    void* __restrict__ Cout, float* __restrict__ stats, int M, int K, int Nc,
    int bx, int by, unsigned short* As, unsigned short* Bs) {
    int tid = threadIdx.x;
    int row0 = by * 128;
    int col0 = bx * 64;
    int lane = tid & 63;
    int w = tid >> 6;
    int wr = (w >> 1) * 64;
    int wc = (w & 1) * 32;
    int fr = lane & 15;
    int kk = (lane >> 4) * 8;

    f32x4 acc[4][2] = {};

    int npass = (A2 != nullptr) ? 2 : 1;
    for (int pass = 0; pass < npass; ++pass) {
        const unsigned short* Ap = pass ? A2 : A;
        const unsigned short* Bp = pass ? B2t : Bt;
        int r = tid >> 1;
        int kc = (tid & 1) * 16;
        int ar = row0 + r;
        if (ar >= M) ar = M - 1;                    // clamp: finite garbage, store-guarded
        int arr = gidx ? gidx[ar] : ar;
        const unsigned short* abase = Ap + (size_t)arr * K + kc;
        int bc = tid & 63;                          // row 0..63 (was tid>>2)
        int bkc = (tid >> 6) * 8;                   // chunk = wave id (balanced slots)
        const unsigned short* bbase = Bp + (size_t)(col0 + bc) * K + bkc;
        for (int k0 = 0; k0 < K; k0 += 32) {
            __syncthreads();
            *(us8_t*)&As[r * LDAP + kc] = *(const us8_t*)(abase + k0);
            *(us8_t*)&As[r * LDAP + kc + 8] = *(const us8_t*)(abase + k0 + 8);
            *(us8_t*)&Bs[bc * LDAP + bkc] = *(const us8_t*)(bbase + k0);
            __syncthreads();
            bf16x8 bf0 = *(bf16x8*)&Bs[(wc + fr) * LDAP + kk];
            bf16x8 bf1 = *(bf16x8*)&Bs[(wc + 16 + fr) * LDAP + kk];
#pragma unroll
            for (int fm = 0; fm < 4; ++fm) {
                bf16x8 af = *(bf16x8*)&As[(wr + fm * 16 + fr) * LDAP + kk];
                acc[fm][0] = __builtin_amdgcn_mfma_f32_16x16x32_bf16(af, bf0, acc[fm][0], 0, 0, 0);
                acc[fm][1] = __builtin_amdgcn_mfma_f32_16x16x32_bf16(af, bf1, acc[fm][1], 0, 0, 0);
            }
        }
    }
    int rq = (lane >> 4) * 4;
    float cs[2] = {0.f, 0.f}, cq[2] = {0.f, 0.f};
#pragma unroll
    for (int fm = 0; fm < 4; ++fm) {
#pragma unroll
        for (int fn = 0; fn < 2; ++fn) {
            int col = col0 + wc + fn * 16 + fr;
#pragma unroll
            for (int i = 0; i < 4; ++i) {
                int row = row0 + wr + fm * 16 + rq + i;
                if (row < M) {
                    float v = acc[fm][fn][i];
                    if (bias) v += bias[col];
                    if (res) v += res[(size_t)row * Nc + col];
                    if (RELU) v = fmaxf(v, 0.f);
                    if (OUTBF16)
                        ((unsigned short*)Cout)[(size_t)row * Nc + col] = f2bf_fast(v);
                    else
                        ((float*)Cout)[(size_t)row * Nc + col] = v;
                    if (STATS) { cs[fn] += v; cq[fn] += v * v; }
                }
            }
        }
    }
    if (STATS) {
#pragma unroll
        for (int fn = 0; fn < 2; ++fn) {
            cs[fn] += __shfl_xor(cs[fn], 16); cs[fn] += __shfl_xor(cs[fn], 32);
            cq[fn] += __shfl_xor(cq[fn], 16); cq[fn] += __shfl_xor(cq[fn], 32);
        }
        if ((lane >> 4) == 0) {
            int col = col0 + wc + fr;
            atomicAdd(&stats[col], cs[0]);
            atomicAdd(&stats[256 + col], cq[0]);
            atomicAdd(&stats[col + 16], cs[1]);
            atomicAdd(&stats[256 + col + 16], cq[1]);
        }
    }
}

// Wrapper for standalone GEMMs
template <bool RELU, bool OUTBF16, bool STATS>
__global__ __launch_bounds__(256) void gemm_mfma_kernel(
    const unsigned short* A, const int* gidx, const unsigned short* Bt,
    const unsigned short* A2, const unsigned short* B2t,
    const float* bias, const float* res, void* Cout, float* stats,
    int M, int K, int Nc) {
    __shared__ unsigned short As[128 * LDAP];
    __shared__ unsigned short Bs[64 * LDAP];
    gemm_body<RELU, OUTBF16, STATS>(A, gidx, Bt, A2, B2t, bias, res, Cout, stats,
                                    M, K, Nc, blockIdx.x, blockIdx.y, As, Bs);
}

// Combined conv+QKV dispatch
__global__ __launch_bounds__(256) void convqkv_kernel(
    const unsigned short* __restrict__ x_bf, const unsigned short* __restrict__ agg_bf,
    const unsigned short* __restrict__ Wrt, const unsigned short* __restrict__ Wnt,
    const unsigned short* __restrict__ Wqkvt,
    const float* __restrict__ b_conv, const float* __restrict__ x,
    float* __restrict__ hB, float* __restrict__ stats,
    const unsigned short* __restrict__ xd_bf, const float* __restrict__ bqkv,
    unsigned short* __restrict__ qkvb, int N, int convBlocks) {
    __shared__ unsigned short As[128 * LDAP];
    __shared__ unsigned short Bs[64 * LDAP];
    int blk = blockIdx.x;
    if (blk < convBlocks) {
        gemm_body<false, false, true>(x_bf, nullptr, Wrt, agg_bf, Wnt, b_conv, x,
                                      hB, stats, N, 256, 256, blk & 3, blk >> 2, As, Bs);
    } else {
        int q = blk - convBlocks;
        gemm_body<false, true, false>(xd_bf, nullptr, Wqkvt, nullptr, nullptr, bqkv, nullptr,
                                      qkvb, nullptr, BT, 256, 768, q % 12, q / 12, As, Bs);
    }
}

// ---------------------------------------------------------------------------
// BN applies (unchanged)
// ---------------------------------------------------------------------------
__global__ void bn_apply_kernel(const float* __restrict__ in, float* __restrict__ out,
                                const float* __restrict__ g, const float* __restrict__ be,
                                const float* __restrict__ stats, int M) {
    int gid = blockIdx.x * 256 + threadIdx.x;
    if (gid >= M * Cc) return;
    int c = gid & (Cc - 1);
    float invM = 1.f / (float)M;
    float mean = stats[c] * invM;
    float var = stats[Cc + c] * invM - mean * mean;
    float sc = g[c] * rsqrtf(var + EPS);
    out[gid] = (in[gid] - mean) * sc + be[c];
}

__global__ void bn12_apply_kernel(const float* __restrict__ hpre,
                                  const float* __restrict__ hattn,
                                  const float* __restrict__ g1, const float* __restrict__ be1,
                                  const float* __restrict__ g2, const float* __restrict__ be2,
                                  const float* __restrict__ stats,
                                  float* __restrict__ out, unsigned short* __restrict__ out_bf,
                                  int M) {
    int gid = blockIdx.x * 256 + threadIdx.x;
    if (gid >= M * Cc) return;
    int c = gid & (Cc - 1);
    float invM = 1.f / (float)M;
    float mean1 = stats[c] * invM;
    float var1 = stats[Cc + c] * invM - mean1 * mean1;
    float sc1 = g1[c] * rsqrtf(var1 + EPS);
    float mean2 = stats[2 * Cc + c] * invM;
    float var2 = stats[3 * Cc + c] * invM - mean2 * mean2;
    float sc2 = g2[c] * rsqrtf(var2 + EPS);
    float v = (hpre[gid] - mean1) * sc1 + be1[c] + (hattn[gid] - mean2) * sc2 + be2[c];
    out[gid] = v;
    out_bf[gid] = f2bf_fast(v);
}

// ---------------------------------------------------------------------------
// MFMA flash attention (unchanged from R14)
// ---------------------------------------------------------------------------
__global__ __launch_bounds__(256) void attn_mfma_kernel(const unsigned short* __restrict__ qkvb,
                                                        const int* __restrict__ bcnt,
                                                        unsigned short* __restrict__ o_bf) {
    const int blk = ((blockIdx.x & 7) << 7) | ((int)blockIdx.x >> 3);  // XCD swizzle (1024 wgs)
    const int qt = blk & 3;
    const int bh = blk >> 2;
    const int b = bh >> 3;
    const int h = bh & 7;
    const int tid = threadIdx.x;
    const int lane = tid & 63;
    const int w = tid >> 6;
    const int fr = lane & 15;
    const int g = lane >> 4;
    const int kk = g * 8;
    const int q0 = qt * 128 + w * 32;

    __shared__ unsigned short Ks[32 * LDAP];
    __shared__ unsigned short Vt[32 * LDAP];
    __shared__ unsigned short Pl[4][2][16 * LDAP];

    const int count = bcnt[b];

    const unsigned short* qp = qkvb + (size_t)(b * Tc + q0 + fr) * 768 + h * 32 + kk;
    bf16x8 qa0 = *(const bf16x8*)qp;
    bf16x8 qa1 = *(const bf16x8*)(qp + (size_t)16 * 768);

    f32x4 op00 = {0.f, 0.f, 0.f, 0.f}, op01 = op00;
    f32x4 op10 = op00, op11 = op00;
    float l0 = 0.f, l1 = 0.f;
    float m0 = -1e30f, m1 = -1e30f;

    const int nt = (count + 31) >> 5;
    for (int t = 0; t < nt; ++t) {
        const int kbase = t * 32;
        __syncthreads();
        {
            int key = tid >> 3;
            int d4 = (tid & 7) * 4;
            const unsigned short* kp =
                qkvb + (size_t)(b * Tc + kbase + key) * 768 + 256 + h * 32 + d4;
            *(ushort4*)&Ks[key * LDAP + d4] = *(const ushort4*)kp;
        }
        {
            int vkey = tid & 31;
            int d0 = (tid >> 5) * 4;
            const unsigned short* vp =
                qkvb + (size_t)(b * Tc + kbase + vkey) * 768 + 512 + h * 32 + d0;
            ushort4 vv = *(const ushort4*)vp;
            Vt[(d0 + 0) * LDAP + vkey] = vv.x;
            Vt[(d0 + 1) * LDAP + vkey] = vv.y;
            Vt[(d0 + 2) * LDAP + vkey] = vv.z;
            Vt[(d0 + 3) * LDAP + vkey] = vv.w;
        }
        __syncthreads();

        bf16x8 ka0 = *(bf16x8*)&Ks[fr * LDAP + kk];
        bf16x8 ka1 = *(bf16x8*)&Ks[(16 + fr) * LDAP + kk];
        f32x4 z = {0.f, 0.f, 0.f, 0.f};
        f32x4 s00 = __builtin_amdgcn_mfma_f32_16x16x32_bf16(ka0, qa0, z, 0, 0, 0);
        f32x4 s10 = __builtin_amdgcn_mfma_f32_16x16x32_bf16(ka1, qa0, z, 0, 0, 0);
        f32x4 s01 = __builtin_amdgcn_mfma_f32_16x16x32_bf16(ka0, qa1, z, 0, 0, 0);
        f32x4 s11 = __builtin_amdgcn_mfma_f32_16x16x32_bf16(ka1, qa1, z, 0, 0, 0);

#pragma unroll
        for (int i = 0; i < 4; ++i) {
            bool v0 = (kbase + g * 4 + i) < count;
            bool v1 = (kbase + 16 + g * 4 + i) < count;
            s00[i] = v0 ? s00[i] : -1e30f;
            s01[i] = v0 ? s01[i] : -1e30f;
            s10[i] = v1 ? s10[i] : -1e30f;
            s11[i] = v1 ? s11[i] : -1e30f;
        }

        float r0_ = fmaxf(fmaxf(fmaxf(s00[0], s00[1]), fmaxf(s00[2], s00[3])),
                          fmaxf(fmaxf(s10[0], s10[1]), fmaxf(s10[2], s10[3])));
        r0_ = fmaxf(r0_, __shfl_xor(r0_, 16));
        r0_ = fmaxf(r0_, __shfl_xor(r0_, 32));
        float mn0 = fmaxf(m0, r0_);
        float c0 = __expf(m0 - mn0);
        m0 = mn0;
        l0 *= c0;
        float p00[4], p10[4];
#pragma unroll
        for (int i = 0; i < 4; ++i) {
            p00[i] = __expf(s00[i] - mn0);
            p10[i] = __expf(s10[i] - mn0);
            l0 += p00[i] + p10[i];
        }
        float r1_ = fmaxf(fmaxf(fmaxf(s01[0], s01[1]), fmaxf(s01[2], s01[3])),
                          fmaxf(fmaxf(s11[0], s11[1]), fmaxf(s11[2], s11[3])));
        r1_ = fmaxf(r1_, __shfl_xor(r1_, 16));
        r1_ = fmaxf(r1_, __shfl_xor(r1_, 32));
        float mn1 = fmaxf(m1, r1_);
        float c1 = __expf(m1 - mn1);
        m1 = mn1;
        l1 *= c1;
        float p01[4], p11[4];
#pragma unroll
        for (int i = 0; i < 4; ++i) {
            p01[i] = __expf(s01[i] - mn1);
            p11[i] = __expf(s11[i] - mn1);
            l1 += p01[i] + p11[i];
        }

        unsigned short* pw0 = &Pl[w][0][0];
        unsigned short* pw1 = &Pl[w][1][0];
        ushort4 q00, q10, q01, q11;
        q00.x = f2bf_fast(p00[0]); q00.y = f2bf_fast(p00[1]);
        q00.z = f2bf_fast(p00[2]); q00.w = f2bf_fast(p00[3]);
        q10.x = f2bf_fast(p10[0]); q10.y = f2bf_fast(p10[1]);
        q10.z = f2bf_fast(p10[2]); q10.w = f2bf_fast(p10[3]);
        q01.x = f2bf_fast(p01[0]); q01.y = f2bf_fast(p01[1]);
        q01.z = f2bf_fast(p01[2]); q01.w = f2bf_fast(p01[3]);
        q11.x = f2bf_fast(p11[0]); q11.y = f2bf_fast(p11[1]);
        q11.z = f2bf_fast(p11[2]); q11.w = f2bf_fast(p11[3]);
        *(ushort4*)&pw0[fr * LDAP + g * 4] = q00;
        *(ushort4*)&pw0[fr * LDAP + 16 + g * 4] = q10;
        *(ushort4*)&pw1[fr * LDAP + g * 4] = q01;
        *(ushort4*)&pw1[fr * LDAP + 16 + g * 4] = q11;

#pragma unroll
        for (int i = 0; i < 4; ++i) {
            float ci0 = __shfl(c0, g * 4 + i);
            float ci1 = __shfl(c1, g * 4 + i);
            op00[i] *= ci0; op01[i] *= ci0;
            op10[i] *= ci1; op11[i] *= ci1;
        }

        asm volatile("s_waitcnt lgkmcnt(0)" ::: "memory");
        __builtin_amdgcn_sched_barrier(0);

        bf16x8 pa0 = *(bf16x8*)&pw0[fr * LDAP + kk];
        bf16x8 pa1 = *(bf16x8*)&pw1[fr * LDAP + kk];
        bf16x8 vb0 = *(bf16x8*)&Vt[fr * LDAP + kk];
        bf16x8 vb1 = *(bf16x8*)&Vt[(16 + fr) * LDAP + kk];
        op00 = __builtin_amdgcn_mfma_f32_16x16x32_bf16(pa0, vb0, op00, 0, 0, 0);
        op01 = __builtin_amdgcn_mfma_f32_16x16x32_bf16(pa0, vb1, op01, 0, 0, 0);
        op10 = __builtin_amdgcn_mfma_f32_16x16x32_bf16(pa1, vb0, op10, 0, 0, 0);
        op11 = __builtin_amdgcn_mfma_f32_16x16x32_bf16(pa1, vb1, op11, 0, 0, 0);
    }

    l0 += __shfl_xor(l0, 16); l0 += __shfl_xor(l0, 32);
    l1 += __shfl_xor(l1, 16); l1 += __shfl_xor(l1, 32);
    float inv0 = 1.f / l0;
    float inv1 = 1.f / l1;
#pragma unroll
    for (int i = 0; i < 4; ++i) {
        float li0 = __shfl(inv0, g * 4 + i);
        float li1 = __shfl(inv1, g * 4 + i);
        size_t row0 = (size_t)(b * Tc + q0 + g * 4 + i);
        size_t row1 = row0 + 16;
        o_bf[row0 * Cc + h * 32 + fr] = f2bf_fast(op00[i] * li0);
        o_bf[row0 * Cc + h * 32 + 16 + fr] = f2bf_fast(op01[i] * li0);
        o_bf[row1 * Cc + h * 32 + fr] = f2bf_fast(op10[i] * li1);
        o_bf[row1 * Cc + h * 32 + 16 + fr] = f2bf_fast(op11[i] * li1);
    }
}

// ---------------------------------------------------------------------------
// Launch (10 dispatches)
// ---------------------------------------------------------------------------
extern "C" void kernel_launch(void* const* d_in, const int* in_sizes, int n_in,
                              void* d_out, int out_size, void* d_ws, size_t ws_size,
                              hipStream_t stream) {
    const float* x      = (const float*)d_in[0];
    const int*   ei     = (const int*)d_in[1];
    const int*   idx    = (const int*)d_in[2];
    const float* W_root = (const float*)d_in[4];
    const float* W_nbr  = (const float*)d_in[5];
    const float* b_conv = (const float*)d_in[6];
    const float* Wq     = (const float*)d_in[7];
    const float* Wk     = (const float*)d_in[8];
    const float* Wv     = (const float*)d_in[9];
    const float* bq     = (const float*)d_in[10];
    const float* bk     = (const float*)d_in[11];
    const float* bv     = (const float*)d_in[12];
    const float* Wo     = (const float*)d_in[13];
    const float* bo     = (const float*)d_in[14];
    const float* W1     = (const float*)d_in[15];
    const float* b1     = (const float*)d_in[16];
    const float* W2     = (const float*)d_in[17];
    const float* b2     = (const float*)d_in[18];
    const float* g1     = (const float*)d_in[19];
    const float* be1    = (const float*)d_in[20];
    const float* g2     = (const float*)d_in[21];
    const float* be2    = (const float*)d_in[22];
    const float* g3     = (const float*)d_in[23];
    const float* be3    = (const float*)d_in[24];

    const int N = in_sizes[0] / Cc;
    const int E = in_sizes[1] / 2;

    // Workspace layout
    float* ws = (float*)d_ws;
    float* hB    = ws;                                       // N*C f32 (h_pre -> out1)
    float* bqkv  = hB + (size_t)N * Cc;                      // 768
    unsigned short* wsq    = (unsigned short*)(bqkv + 768);  // 655360
    unsigned short* x_bf   = wsq + 655360;                   // N*C
    unsigned short* hB_bf  = x_bf + (size_t)N * Cc;          // N*C
    unsigned short* hid_bf = hB_bf + (size_t)N * Cc;         // N*2C
    unsigned short* xd_bf  = hid_bf + (size_t)N * 2 * Cc;    // BT*C (also attn out)
    unsigned short* qkvb   = xd_bf + (size_t)BT * Cc;        // BT*768
    int*   bcnt   = (int*)(qkvb + (size_t)BT * 768);         // 32
    float* stats  = (float*)(bcnt + 32);                     // 6*C, start of zeroed region
    int*   cursor = (int*)(stats + 6 * Cc);                  // N (degree counters), zeroed
    int*   csr    = cursor + N;                              // N*CSTRIDE
    float* bufA   = (float*)d_out;                           // N*C scratch
    unsigned short* agg_bf = (unsigned short*)d_out;
    unsigned short* ao = xd_bf;

    const unsigned short* Wrt   = wsq;
    const unsigned short* Wnt   = wsq + 65536;
    const unsigned short* Wqkvt = wsq + 131072;
    const unsigned short* Wot   = wsq + 327680;
    const unsigned short* W1t   = wsq + 393216;
    const unsigned short* W2t   = wsq + 524288;

    const int nzero = 6 * Cc + N;          // stats floats + cursor ints (contiguous)
    const int nzero4 = (nzero + 3) / 4;

    // 1: mega-fused prologue
    {
        int total = 656128 + N * 32 + 64 + nzero4;
        wcvt_fused_kernel<<<(total + 255) / 256, 256, 0, stream>>>(
            W_root, W_nbr, Wq, Wk, Wv, Wo, W1, W2, bq, bk, bv, wsq, bqkv,
            x, idx, x_bf, xd_bf, bcnt, (int*)stats, N, nzero4);
    }

    // 2: direct CSR fill (cursor -> degree)
    fill_csr_kernel<<<(E + 255) / 256, 256, 0, stream>>>(ei, cursor, csr, E);

    // 3: gather (agg -> bf16 in d_out region)
    gather_kernel<<<(N + 3) / 4, 256, 0, stream>>>(x_bf, csr, cursor, agg_bf, N);

    // 4: combined conv GEMM (+BN1 stats) and QKV GEMM (->bf16)
    {
        int convBlocks = 4 * ((N + 127) / 128);
        int qkvBlocks = 12 * (BT / 128);
        convqkv_kernel<<<convBlocks + qkvBlocks, 256, 0, stream>>>(
            x_bf, agg_bf, Wrt, Wnt, Wqkvt, b_conv, x, hB, stats,
            xd_bf, bqkv, qkvb, N, convBlocks);
    }

    // 5: attention
    attn_mfma_kernel<<<Bc * Hc * 4, 256, 0, stream>>>(qkvb, bcnt, ao);

    // 6: Wo GEMM + BN2 stats
    {
        dim3 grid(Cc / 64, (N + 127) / 128);
        gemm_mfma_kernel<false, false, true><<<grid, 256, 0, stream>>>(
            ao, idx, Wot, nullptr, nullptr, bo, x, bufA, stats + 2 * Cc, N, Cc, Cc);
    }

    // 7: fused BN1+BN2 apply -> out1 (f32 hB + bf16 hB_bf)
    bn12_apply_kernel<<<(N * Cc + 255) / 256, 256, 0, stream>>>(
        hB, bufA, g1, be1, g2, be2, stats, hB, hB_bf, N);

    // 8: W1 GEMM (relu) -> bf16 hid
    {
        dim3 grid(512 / 64, (N + 127) / 128);
        gemm_mfma_kernel<true, true, false><<<grid, 256, 0, stream>>>(
            hB_bf, nullptr, W1t, nullptr, nullptr, b1, nullptr, hid_bf, nullptr, N, Cc, 512);
    }

    // 9: W2 GEMM + BN3 stats
    {
        dim3 grid(Cc / 64, (N + 127) / 128);
        gemm_mfma_kernel<false, false, true><<<grid, 256, 0, stream>>>(
            hid_bf, nullptr, W2t, nullptr, nullptr, b2, hB, bufA, stats + 4 * Cc, N, 512, Cc);
    }

    // 10: BN3 apply in place on d_out
    bn_apply_kernel<<<(N * Cc + 255) / 256, 256, 0, stream>>>(
        bufA, bufA, g3, be3, stats + 4 * Cc, N);
}

// Round 17
// 224.699 us; speedup vs baseline: 1.1528x; 1.0261x over previous
//
#include <hip/hip_runtime.h>
#include <hip/hip_bf16.h>
#include <math.h>

#define Bc 32
#define Tc 512
#define Cc 256
#define Hc 8
#define BT (Bc * Tc)
#define EPS 1e-5f
#define LDAP 40      // LDS row stride (ushorts, 80B): bank-group(row,chunk)=(5r+c)%8
#define CSTRIDE 128  // fixed CSR row stride

typedef __bf16 bf16x8 __attribute__((ext_vector_type(8)));
typedef float f32x4 __attribute__((ext_vector_type(4)));
typedef unsigned short us8_t __attribute__((ext_vector_type(8)));

__device__ inline unsigned short f2bf(float f) {
    unsigned int u = __float_as_uint(f);
    u += 0x7fffu + ((u >> 16) & 1u);
    return (unsigned short)(u >> 16);
}
__device__ inline unsigned short f2bf_fast(float f) {
    __bf16 h = (__bf16)f;
    return __builtin_bit_cast(unsigned short, h);
}
__device__ inline float bf2f(unsigned short u) {
    return __uint_as_float((unsigned int)u << 16);
}

// ---------------------------------------------------------------------------
// Mega-fused prologue (unchanged)
// ---------------------------------------------------------------------------
__global__ void wcvt_fused_kernel(const float* __restrict__ Wr, const float* __restrict__ Wn,
                                  const float* __restrict__ Wq, const float* __restrict__ Wk,
                                  const float* __restrict__ Wv, const float* __restrict__ Wo,
                                  const float* __restrict__ W1, const float* __restrict__ W2,
                                  const float* __restrict__ bq, const float* __restrict__ bk,
                                  const float* __restrict__ bv,
                                  unsigned short* __restrict__ wsq, float* __restrict__ bqkv,
                                  const float* __restrict__ x, const int* __restrict__ idx,
                                  unsigned short* __restrict__ x_bf,
                                  unsigned short* __restrict__ xd_bf,
                                  int* __restrict__ bcnt, int* __restrict__ zbase,
                                  int N, int nzero4) {
    const float scale = 0.17677669529663687f;  // 1/sqrt(32)
    int gid = blockIdx.x * 256 + threadIdx.x;
    const int X0 = 656128 + N * 32;
    const int XZ = X0 + 64;
    if (gid >= XZ) {
        int j = gid - XZ;
        if (j < nzero4) {
            int4 z = {0, 0, 0, 0};
            *(int4*)&zbase[j * 4] = z;
        }
        return;
    }
    if (gid >= X0) {
        int b = gid - X0;
        if (b >= 32) return;
        int lo = 0, hi = N, v0 = b << 9;
        while (lo < hi) { int mid = (lo + hi) >> 1; if (idx[mid] < v0) lo = mid + 1; else hi = mid; }
        int s = lo;
        lo = 0; hi = N; int v1 = (b + 1) << 9;
        while (lo < hi) { int mid = (lo + hi) >> 1; if (idx[mid] < v1) lo = mid + 1; else hi = mid; }
        bcnt[b] = lo - s;
        return;
    }
    if (gid >= 656128) {
        int j = gid - 656128;
        int i = j >> 5;
        if (i >= N) return;
        int c8 = (j & 31) * 8;
        const float* sp = x + (size_t)i * Cc + c8;
        float4 f0 = *(const float4*)sp;
        float4 f1 = *(const float4*)(sp + 4);
        us8_t pk;
        pk[0] = f2bf_fast(f0.x); pk[1] = f2bf_fast(f0.y);
        pk[2] = f2bf_fast(f0.z); pk[3] = f2bf_fast(f0.w);
        pk[4] = f2bf_fast(f1.x); pk[5] = f2bf_fast(f1.y);
        pk[6] = f2bf_fast(f1.z); pk[7] = f2bf_fast(f1.w);
        *(us8_t*)&x_bf[(size_t)i * Cc + c8] = pk;
        int slot = idx[i];
        *(us8_t*)&xd_bf[(size_t)slot * Cc + c8] = pk;
        return;
    }
    if (gid >= 655360) {
        int j = gid - 655360;
        bqkv[j] = (j < 256) ? bq[j] * scale : (j < 512 ? bk[j - 256] : bv[j - 512]);
        return;
    }
    const float* src; int base, K, N_; float mul = 1.f;
    if (gid < 65536)       { src = Wr; base = 0;      K = 256; N_ = 256; }
    else if (gid < 131072) { src = Wn; base = 65536;  K = 256; N_ = 256; }
    else if (gid < 196608) { src = Wq; base = 131072; K = 256; N_ = 256; mul = scale; }
    else if (gid < 262144) { src = Wk; base = 196608; K = 256; N_ = 256; }
    else if (gid < 327680) { src = Wv; base = 262144; K = 256; N_ = 256; }
    else if (gid < 393216) { src = Wo; base = 327680; K = 256; N_ = 256; }
    else if (gid < 524288) { src = W1; base = 393216; K = 256; N_ = 512; }
    else                   { src = W2; base = 524288; K = 512; N_ = 256; }
    int loc = gid - base;
    int n = loc / K, k = loc % K;
    wsq[gid] = f2bf(src[(size_t)k * N_ + n] * mul);
}

// ---------------------------------------------------------------------------
// Direct fixed-stride CSR fill + gather (unchanged)
// ---------------------------------------------------------------------------
__global__ void fill_csr_kernel(const int* __restrict__ ei, int* __restrict__ cursor,
                                int* __restrict__ csr, int E) {
    int e = blockIdx.x * 256 + threadIdx.x;
    if (e >= E) return;
    int dst = ei[E + e];
    int pos = atomicAdd(&cursor[dst], 1);
    if (pos < CSTRIDE) csr[(size_t)dst * CSTRIDE + pos] = ei[e];
}

__global__ __launch_bounds__(256) void gather_kernel(const unsigned short* __restrict__ x_bf,
                                                     const int* __restrict__ csr,
                                                     const int* __restrict__ cursor,
                                                     unsigned short* __restrict__ agg_bf,
                                                     int N) {
    int i = blockIdx.x * 4 + (threadIdx.x >> 6);
    if (i >= N) return;
    int l4 = (threadIdx.x & 63) * 4;
    int dcount = cursor[i];
    if (dcount > CSTRIDE) dcount = CSTRIDE;
    const int* row = csr + (size_t)i * CSTRIDE;
    f32x4 a0 = {0.f, 0.f, 0.f, 0.f}, a1 = a0, a2 = a0, a3 = a0;
    int e = 0;
    for (; e + 4 <= dcount; e += 4) {
        int i0 = row[e + 0];
        int i1 = row[e + 1];
        int i2 = row[e + 2];
        int i3 = row[e + 3];
        ushort4 u0 = *(const ushort4*)(x_bf + (size_t)i0 * Cc + l4);
        ushort4 u1 = *(const ushort4*)(x_bf + (size_t)i1 * Cc + l4);
        ushort4 u2 = *(const ushort4*)(x_bf + (size_t)i2 * Cc + l4);
        ushort4 u3 = *(const ushort4*)(x_bf + (size_t)i3 * Cc + l4);
        a0[0] += bf2f(u0.x); a0[1] += bf2f(u0.y); a0[2] += bf2f(u0.z); a0[3] += bf2f(u0.w);
        a1[0] += bf2f(u1.x); a1[1] += bf2f(u1.y); a1[2] += bf2f(u1.z); a1[3] += bf2f(u1.w);
        a2[0] += bf2f(u2.x); a2[1] += bf2f(u2.y); a2[2] += bf2f(u2.z); a2[3] += bf2f(u2.w);
        a3[0] += bf2f(u3.x); a3[1] += bf2f(u3.y); a3[2] += bf2f(u3.z); a3[3] += bf2f(u3.w);
    }
    for (; e < dcount; ++e) {
        ushort4 u = *(const ushort4*)(x_bf + (size_t)row[e] * Cc + l4);
        a0[0] += bf2f(u.x); a0[1] += bf2f(u.y); a0[2] += bf2f(u.z); a0[3] += bf2f(u.w);
    }
    f32x4 s = (a0 + a1) + (a2 + a3);
    ushort4 w4;
    w4.x = f2bf_fast(s[0]); w4.y = f2bf_fast(s[1]);
    w4.z = f2bf_fast(s[2]); w4.w = f2bf_fast(s[3]);
    *(ushort4*)&agg_bf[(size_t)i * Cc + l4] = w4;
}

// ---------------------------------------------------------------------------
// GEMM body (R14 core + two changes):
//  (1) B-staging rows permuted within wave so each 16-lane phase covers
//      even/odd-spaced rows -> (5r+c)%8 tiles all 8 bank-groups 2x (free);
//      quad-per-row 64B global coalescing identical to R14.
//  (2) Register prefetch of next K-tile issued after produce-barrier.
// ---------------------------------------------------------------------------
template <bool RELU, bool OUTBF16, bool STATS>
__device__ __forceinline__ void gemm_body(
    const unsigned short* __restrict__ A, const int* __restrict__ gidx,
    const unsigned short* __restrict__ Bt,
    const unsigned short* __restrict__ A2, const unsigned short* __restrict__ B2t,
    const float* __restrict__ bias, const float* __restrict__ res,
    void* __restrict__ Cout, float* __restrict__ stats, int M, int K, int Nc,
    int bx, int by, unsigned short* As, unsigned short* Bs) {
    int tid = threadIdx.x;
    int row0 = by * 128;
    int col0 = bx * 64;
    int lane = tid & 63;
    int w = tid >> 6;
    int wr = (w >> 1) * 64;
    int wc = (w & 1) * 32;
    int fr = lane & 15;
    int kk = (lane >> 4) * 8;

    f32x4 acc[4][2] = {};

    // A staging (R14): 2 threads/row, 32B each (bank-free, verified)
    int r = tid >> 1;
    int kc = (tid & 1) * 16;
    // B staging: quad q covers all 4 chunks of one row (64B coalesced);
    // row order within wave: {0,2,4,6},{8,10,12,14},{1,3,5,7},{9,11,13,15}
    int ql = (tid >> 2) & 15;
    int bc = ((tid >> 6) << 4) + ((ql & 3) << 1) + (((ql >> 2) & 1) << 3) + (ql >> 3);
    int bkc = (tid & 3) * 8;

    int npass = (A2 != nullptr) ? 2 : 1;
    for (int pass = 0; pass < npass; ++pass) {
        const unsigned short* Ap = pass ? A2 : A;
        const unsigned short* Bp = pass ? B2t : Bt;
        int ar = row0 + r;
        if (ar >= M) ar = M - 1;                    // clamp: finite garbage, store-guarded
        int arr = gidx ? gidx[ar] : ar;
        const unsigned short* abase = Ap + (size_t)arr * K + kc;
        const unsigned short* bbase = Bp + (size_t)(col0 + bc) * K + bkc;
        us8_t pa0 = *(const us8_t*)(abase);
        us8_t pa1 = *(const us8_t*)(abase + 8);
        us8_t pb  = *(const us8_t*)(bbase);
        for (int k0 = 0; k0 < K; k0 += 32) {
            __syncthreads();
            *(us8_t*)&As[r * LDAP + kc] = pa0;
            *(us8_t*)&As[r * LDAP + kc + 8] = pa1;
            *(us8_t*)&Bs[bc * LDAP + bkc] = pb;
            __syncthreads();
            int k1 = k0 + 32;
            if (k1 < K) {        // prefetch next K-tile; latency hidden by MFMAs
                pa0 = *(const us8_t*)(abase + k1);
                pa1 = *(const us8_t*)(abase + k1 + 8);
                pb  = *(const us8_t*)(bbase + k1);
            }
            bf16x8 bf0 = *(bf16x8*)&Bs[(wc + fr) * LDAP + kk];
            bf16x8 bf1 = *(bf16x8*)&Bs[(wc + 16 + fr) * LDAP + kk];
#pragma unroll
            for (int fm = 0; fm < 4; ++fm) {
                bf16x8 af = *(bf16x8*)&As[(wr + fm * 16 + fr) * LDAP + kk];
                acc[fm][0] = __builtin_amdgcn_mfma_f32_16x16x32_bf16(af, bf0, acc[fm][0], 0, 0, 0);
                acc[fm][1] = __builtin_amdgcn_mfma_f32_16x16x32_bf16(af, bf1, acc[fm][1], 0, 0, 0);
            }
        }
    }
    int rq = (lane >> 4) * 4;
    float cs[2] = {0.f, 0.f}, cq[2] = {0.f, 0.f};
#pragma unroll
    for (int fm = 0; fm < 4; ++fm) {
#pragma unroll
        for (int fn = 0; fn < 2; ++fn) {
            int col = col0 + wc + fn * 16 + fr;
#pragma unroll
            for (int i = 0; i < 4; ++i) {
                int row = row0 + wr + fm * 16 + rq + i;
                if (row < M) {
                    float v = acc[fm][fn][i];
                    if (bias) v += bias[col];
                    if (res) v += res[(size_t)row * Nc + col];
                    if (RELU) v = fmaxf(v, 0.f);
                    if (OUTBF16)
                        ((unsigned short*)Cout)[(size_t)row * Nc + col] = f2bf_fast(v);
                    else
                        ((float*)Cout)[(size_t)row * Nc + col] = v;
                    if (STATS) { cs[fn] += v; cq[fn] += v * v; }
                }
            }
        }
    }
    if (STATS) {
#pragma unroll
        for (int fn = 0; fn < 2; ++fn) {
            cs[fn] += __shfl_xor(cs[fn], 16); cs[fn] += __shfl_xor(cs[fn], 32);
            cq[fn] += __shfl_xor(cq[fn], 16); cq[fn] += __shfl_xor(cq[fn], 32);
        }
        if ((lane >> 4) == 0) {
            int col = col0 + wc + fr;
            atomicAdd(&stats[col], cs[0]);
            atomicAdd(&stats[256 + col], cq[0]);
            atomicAdd(&stats[col + 16], cs[1]);
            atomicAdd(&stats[256 + col + 16], cq[1]);
        }
    }
}

// Wrapper for standalone GEMMs
template <bool RELU, bool OUTBF16, bool STATS>
__global__ __launch_bounds__(256) void gemm_mfma_kernel(
    const unsigned short* A, const int* gidx, const unsigned short* Bt,
    const unsigned short* A2, const unsigned short* B2t,
    const float* bias, const float* res, void* Cout, float* stats,
    int M, int K, int Nc) {
    __shared__ unsigned short As[128 * LDAP];
    __shared__ unsigned short Bs[64 * LDAP];
    gemm_body<RELU, OUTBF16, STATS>(A, gidx, Bt, A2, B2t, bias, res, Cout, stats,
                                    M, K, Nc, blockIdx.x, blockIdx.y, As, Bs);
}

// Combined conv+QKV dispatch
__global__ __launch_bounds__(256) void convqkv_kernel(
    const unsigned short* __restrict__ x_bf, const unsigned short* __restrict__ agg_bf,
    const unsigned short* __restrict__ Wrt, const unsigned short* __restrict__ Wnt,
    const unsigned short* __restrict__ Wqkvt,
    const float* __restrict__ b_conv, const float* __restrict__ x,
    float* __restrict__ hB, float* __restrict__ stats,
    const unsigned short* __restrict__ xd_bf, const float* __restrict__ bqkv,
    unsigned short* __restrict__ qkvb, int N, int convBlocks) {
    __shared__ unsigned short As[128 * LDAP];
    __shared__ unsigned short Bs[64 * LDAP];
    int blk = blockIdx.x;
    if (blk < convBlocks) {
        gemm_body<false, false, true>(x_bf, nullptr, Wrt, agg_bf, Wnt, b_conv, x,
                                      hB, stats, N, 256, 256, blk & 3, blk >> 2, As, Bs);
    } else {
        int q = blk - convBlocks;
        gemm_body<false, true, false>(xd_bf, nullptr, Wqkvt, nullptr, nullptr, bqkv, nullptr,
                                      qkvb, nullptr, BT, 256, 768, q % 12, q / 12, As, Bs);
    }
}

// ---------------------------------------------------------------------------
// BN applies (unchanged)
// ---------------------------------------------------------------------------
__global__ void bn_apply_kernel(const float* __restrict__ in, float* __restrict__ out,
                                const float* __restrict__ g, const float* __restrict__ be,
                                const float* __restrict__ stats, int M) {
    int gid = blockIdx.x * 256 + threadIdx.x;
    if (gid >= M * Cc) return;
    int c = gid & (Cc - 1);
    float invM = 1.f / (float)M;
    float mean = stats[c] * invM;
    float var = stats[Cc + c] * invM - mean * mean;
    float sc = g[c] * rsqrtf(var + EPS);
    out[gid] = (in[gid] - mean) * sc + be[c];
}

__global__ void bn12_apply_kernel(const float* __restrict__ hpre,
                                  const float* __restrict__ hattn,
                                  const float* __restrict__ g1, const float* __restrict__ be1,
                                  const float* __restrict__ g2, const float* __restrict__ be2,
                                  const float* __restrict__ stats,
                                  float* __restrict__ out, unsigned short* __restrict__ out_bf,
                                  int M) {
    int gid = blockIdx.x * 256 + threadIdx.x;
    if (gid >= M * Cc) return;
    int c = gid & (Cc - 1);
    float invM = 1.f / (float)M;
    float mean1 = stats[c] * invM;
    float var1 = stats[Cc + c] * invM - mean1 * mean1;
    float sc1 = g1[c] * rsqrtf(var1 + EPS);
    float mean2 = stats[2 * Cc + c] * invM;
    float var2 = stats[3 * Cc + c] * invM - mean2 * mean2;
    float sc2 = g2[c] * rsqrtf(var2 + EPS);
    float v = (hpre[gid] - mean1) * sc1 + be1[c] + (hattn[gid] - mean2) * sc2 + be2[c];
    out[gid] = v;
    out_bf[gid] = f2bf_fast(v);
}

// ---------------------------------------------------------------------------
// MFMA flash attention (unchanged)
// ---------------------------------------------------------------------------
__global__ __launch_bounds__(256) void attn_mfma_kernel(const unsigned short* __restrict__ qkvb,
                                                        const int* __restrict__ bcnt,
                                                        unsigned short* __restrict__ o_bf) {
    const int blk = ((blockIdx.x & 7) << 7) | ((int)blockIdx.x >> 3);  // XCD swizzle (1024 wgs)
    const int qt = blk & 3;
    const int bh = blk >> 2;
    const int b = bh >> 3;
    const int h = bh & 7;
    const int tid = threadIdx.x;
    const int lane = tid & 63;
    const int w = tid >> 6;
    const int fr = lane & 15;
    const int g = lane >> 4;
    const int kk = g * 8;
    const int q0 = qt * 128 + w * 32;

    __shared__ unsigned short Ks[32 * LDAP];
    __shared__ unsigned short Vt[32 * LDAP];
    __shared__ unsigned short Pl[4][2][16 * LDAP];

    const int count = bcnt[b];

    const unsigned short* qp = qkvb + (size_t)(b * Tc + q0 + fr) * 768 + h * 32 + kk;
    bf16x8 qa0 = *(const bf16x8*)qp;
    bf16x8 qa1 = *(const bf16x8*)(qp + (size_t)16 * 768);

    f32x4 op00 = {0.f, 0.f, 0.f, 0.f}, op01 = op00;
    f32x4 op10 = op00, op11 = op00;
    float l0 = 0.f, l1 = 0.f;
    float m0 = -1e30f, m1 = -1e30f;

    const int nt = (count + 31) >> 5;
    for (int t = 0; t < nt; ++t) {
        const int kbase = t * 32;
        __syncthreads();
        {
            int key = tid >> 3;
            int d4 = (tid & 7) * 4;
            const unsigned short* kp =
                qkvb + (size_t)(b * Tc + kbase + key) * 768 + 256 + h * 32 + d4;
            *(ushort4*)&Ks[key * LDAP + d4] = *(const ushort4*)kp;
        }
        {
            int vkey = tid & 31;
            int d0 = (tid >> 5) * 4;
            const unsigned short* vp =
                qkvb + (size_t)(b * Tc + kbase + vkey) * 768 + 512 + h * 32 + d0;
            ushort4 vv = *(const ushort4*)vp;
            Vt[(d0 + 0) * LDAP + vkey] = vv.x;
            Vt[(d0 + 1) * LDAP + vkey] = vv.y;
            Vt[(d0 + 2) * LDAP + vkey] = vv.z;
            Vt[(d0 + 3) * LDAP + vkey] = vv.w;
        }
        __syncthreads();

        bf16x8 ka0 = *(bf16x8*)&Ks[fr * LDAP + kk];
        bf16x8 ka1 = *(bf16x8*)&Ks[(16 + fr) * LDAP + kk];
        f32x4 z = {0.f, 0.f, 0.f, 0.f};
        f32x4 s00 = __builtin_amdgcn_mfma_f32_16x16x32_bf16(ka0, qa0, z, 0, 0, 0);
        f32x4 s10 = __builtin_amdgcn_mfma_f32_16x16x32_bf16(ka1, qa0, z, 0, 0, 0);
        f32x4 s01 = __builtin_amdgcn_mfma_f32_16x16x32_bf16(ka0, qa1, z, 0, 0, 0);
        f32x4 s11 = __builtin_amdgcn_mfma_f32_16x16x32_bf16(ka1, qa1, z, 0, 0, 0);

#pragma unroll
        for (int i = 0; i < 4; ++i) {
            bool v0 = (kbase + g * 4 + i) < count;
            bool v1 = (kbase + 16 + g * 4 + i) < count;
            s00[i] = v0 ? s00[i] : -1e30f;
            s01[i] = v0 ? s01[i] : -1e30f;
            s10[i] = v1 ? s10[i] : -1e30f;
            s11[i] = v1 ? s11[i] : -1e30f;
        }

        float r0_ = fmaxf(fmaxf(fmaxf(s00[0], s00[1]), fmaxf(s00[2], s00[3])),
                          fmaxf(fmaxf(s10[0], s10[1]), fmaxf(s10[2], s10[3])));
        r0_ = fmaxf(r0_, __shfl_xor(r0_, 16));
        r0_ = fmaxf(r0_, __shfl_xor(r0_, 32));
        float mn0 = fmaxf(m0, r0_);
        float c0 = __expf(m0 - mn0);
        m0 = mn0;
        l0 *= c0;
        float p00[4], p10[4];
#pragma unroll
        for (int i = 0; i < 4; ++i) {
            p00[i] = __expf(s00[i] - mn0);
            p10[i] = __expf(s10[i] - mn0);
            l0 += p00[i] + p10[i];
        }
        float r1_ = fmaxf(fmaxf(fmaxf(s01[0], s01[1]), fmaxf(s01[2], s01[3])),
                          fmaxf(fmaxf(s11[0], s11[1]), fmaxf(s11[2], s11[3])));
        r1_ = fmaxf(r1_, __shfl_xor(r1_, 16));
        r1_ = fmaxf(r1_, __shfl_xor(r1_, 32));
        float mn1 = fmaxf(m1, r1_);
        float c1 = __expf(m1 - mn1);
        m1 = mn1;
        l1 *= c1;
        float p01[4], p11[4];
#pragma unroll
        for (int i = 0; i < 4; ++i) {
            p01[i] = __expf(s01[i] - mn1);
            p11[i] = __expf(s11[i] - mn1);
            l1 += p01[i] + p11[i];
        }

        unsigned short* pw0 = &Pl[w][0][0];
        unsigned short* pw1 = &Pl[w][1][0];
        ushort4 q00, q10, q01, q11;
        q00.x = f2bf_fast(p00[0]); q00.y = f2bf_fast(p00[1]);
        q00.z = f2bf_fast(p00[2]); q00.w = f2bf_fast(p00[3]);
        q10.x = f2bf_fast(p10[0]); q10.y = f2bf_fast(p10[1]);
        q10.z = f2bf_fast(p10[2]); q10.w = f2bf_fast(p10[3]);
        q01.x = f2bf_fast(p01[0]); q01.y = f2bf_fast(p01[1]);
        q01.z = f2bf_fast(p01[2]); q01.w = f2bf_fast(p01[3]);
        q11.x = f2bf_fast(p11[0]); q11.y = f2bf_fast(p11[1]);
        q11.z = f2bf_fast(p11[2]); q11.w = f2bf_fast(p11[3]);
        *(ushort4*)&pw0[fr * LDAP + g * 4] = q00;
        *(ushort4*)&pw0[fr * LDAP + 16 + g * 4] = q10;
        *(ushort4*)&pw1[fr * LDAP + g * 4] = q01;
        *(ushort4*)&pw1[fr * LDAP + 16 + g * 4] = q11;

#pragma unroll
        for (int i = 0; i < 4; ++i) {
            float ci0 = __shfl(c0, g * 4 + i);
            float ci1 = __shfl(c1, g * 4 + i);
            op00[i] *= ci0; op01[i] *= ci0;
            op10[i] *= ci1; op11[i] *= ci1;
        }

        asm volatile("s_waitcnt lgkmcnt(0)" ::: "memory");
        __builtin_amdgcn_sched_barrier(0);

        bf16x8 pa0 = *(bf16x8*)&pw0[fr * LDAP + kk];
        bf16x8 pa1 = *(bf16x8*)&pw1[fr * LDAP + kk];
        bf16x8 vb0 = *(bf16x8*)&Vt[fr * LDAP + kk];
        bf16x8 vb1 = *(bf16x8*)&Vt[(16 + fr) * LDAP + kk];
        op00 = __builtin_amdgcn_mfma_f32_16x16x32_bf16(pa0, vb0, op00, 0, 0, 0);
        op01 = __builtin_amdgcn_mfma_f32_16x16x32_bf16(pa0, vb1, op01, 0, 0, 0);
        op10 = __builtin_amdgcn_mfma_f32_16x16x32_bf16(pa1, vb0, op10, 0, 0, 0);
        op11 = __builtin_amdgcn_mfma_f32_16x16x32_bf16(pa1, vb1, op11, 0, 0, 0);
    }

    l0 += __shfl_xor(l0, 16); l0 += __shfl_xor(l0, 32);
    l1 += __shfl_xor(l1, 16); l1 += __shfl_xor(l1, 32);
    float inv0 = 1.f / l0;
    float inv1 = 1.f / l1;
#pragma unroll
    for (int i = 0; i < 4; ++i) {
        float li0 = __shfl(inv0, g * 4 + i);
        float li1 = __shfl(inv1, g * 4 + i);
        size_t row0 = (size_t)(b * Tc + q0 + g * 4 + i);
        size_t row1 = row0 + 16;
        o_bf[row0 * Cc + h * 32 + fr] = f2bf_fast(op00[i] * li0);
        o_bf[row0 * Cc + h * 32 + 16 + fr] = f2bf_fast(op01[i] * li0);
        o_bf[row1 * Cc + h * 32 + fr] = f2bf_fast(op10[i] * li1);
        o_bf[row1 * Cc + h * 32 + 16 + fr] = f2bf_fast(op11[i] * li1);
    }
}

// ---------------------------------------------------------------------------
// Launch (10 dispatches)
// ---------------------------------------------------------------------------
extern "C" void kernel_launch(void* const* d_in, const int* in_sizes, int n_in,
                              void* d_out, int out_size, void* d_ws, size_t ws_size,
                              hipStream_t stream) {
    const float* x      = (const float*)d_in[0];
    const int*   ei     = (const int*)d_in[1];
    const int*   idx    = (const int*)d_in[2];
    const float* W_root = (const float*)d_in[4];
    const float* W_nbr  = (const float*)d_in[5];
    const float* b_conv = (const float*)d_in[6];
    const float* Wq     = (const float*)d_in[7];
    const float* Wk     = (const float*)d_in[8];
    const float* Wv     = (const float*)d_in[9];
    const float* bq     = (const float*)d_in[10];
    const float* bk     = (const float*)d_in[11];
    const float* bv     = (const float*)d_in[12];
    const float* Wo     = (const float*)d_in[13];
    const float* bo     = (const float*)d_in[14];
    const float* W1     = (const float*)d_in[15];
    const float* b1     = (const float*)d_in[16];
    const float* W2     = (const float*)d_in[17];
    const float* b2     = (const float*)d_in[18];
    const float* g1     = (const float*)d_in[19];
    const float* be1    = (const float*)d_in[20];
    const float* g2     = (const float*)d_in[21];
    const float* be2    = (const float*)d_in[22];
    const float* g3     = (const float*)d_in[23];
    const float* be3    = (const float*)d_in[24];

    const int N = in_sizes[0] / Cc;
    const int E = in_sizes[1] / 2;

    // Workspace layout
    float* ws = (float*)d_ws;
    float* hB    = ws;                                       // N*C f32 (h_pre -> out1)
    float* bqkv  = hB + (size_t)N * Cc;                      // 768
    unsigned short* wsq    = (unsigned short*)(bqkv + 768);  // 655360
    unsigned short* x_bf   = wsq + 655360;                   // N*C
    unsigned short* hB_bf  = x_bf + (size_t)N * Cc;          // N*C
    unsigned short* hid_bf = hB_bf + (size_t)N * Cc;         // N*2C
    unsigned short* xd_bf  = hid_bf + (size_t)N * 2 * Cc;    // BT*C (also attn out)
    unsigned short* qkvb   = xd_bf + (size_t)BT * Cc;        // BT*768
    int*   bcnt   = (int*)(qkvb + (size_t)BT * 768);         // 32
    float* stats  = (float*)(bcnt + 32);                     // 6*C, start of zeroed region
    int*   cursor = (int*)(stats + 6 * Cc);                  // N (degree counters), zeroed
    int*   csr    = cursor + N;                              // N*CSTRIDE
    float* bufA   = (float*)d_out;                           // N*C scratch
    unsigned short* agg_bf = (unsigned short*)d_out;
    unsigned short* ao = xd_bf;

    const unsigned short* Wrt   = wsq;
    const unsigned short* Wnt   = wsq + 65536;
    const unsigned short* Wqkvt = wsq + 131072;
    const unsigned short* Wot   = wsq + 327680;
    const unsigned short* W1t   = wsq + 393216;
    const unsigned short* W2t   = wsq + 524288;

    const int nzero = 6 * Cc + N;          // stats floats + cursor ints (contiguous)
    const int nzero4 = (nzero + 3) / 4;

    // 1: mega-fused prologue
    {
        int total = 656128 + N * 32 + 64 + nzero4;
        wcvt_fused_kernel<<<(total + 255) / 256, 256, 0, stream>>>(
            W_root, W_nbr, Wq, Wk, Wv, Wo, W1, W2, bq, bk, bv, wsq, bqkv,
            x, idx, x_bf, xd_bf, bcnt, (int*)stats, N, nzero4);
    }

    // 2: direct CSR fill (cursor -> degree)
    fill_csr_kernel<<<(E + 255) / 256, 256, 0, stream>>>(ei, cursor, csr, E);

    // 3: gather (agg -> bf16 in d_out region)
    gather_kernel<<<(N + 3) / 4, 256, 0, stream>>>(x_bf, csr, cursor, agg_bf, N);

    // 4: combined conv GEMM (+BN1 stats) and QKV GEMM (->bf16)
    {
        int convBlocks = 4 * ((N + 127) / 128);
        int qkvBlocks = 12 * (BT / 128);
        convqkv_kernel<<<convBlocks + qkvBlocks, 256, 0, stream>>>(
            x_bf, agg_bf, Wrt, Wnt, Wqkvt, b_conv, x, hB, stats,
            xd_bf, bqkv, qkvb, N, convBlocks);
    }

    // 5: attention
    attn_mfma_kernel<<<Bc * Hc * 4, 256, 0, stream>>>(qkvb, bcnt, ao);

    // 6: Wo GEMM + BN2 stats
    {
        dim3 grid(Cc / 64, (N + 127) / 128);
        gemm_mfma_kernel<false, false, true><<<grid, 256, 0, stream>>>(
            ao, idx, Wot, nullptr, nullptr, bo, x, bufA, stats + 2 * Cc, N, Cc, Cc);
    }

    // 7: fused BN1+BN2 apply -> out1 (f32 hB + bf16 hB_bf)
    bn12_apply_kernel<<<(N * Cc + 255) / 256, 256, 0, stream>>>(
        hB, bufA, g1, be1, g2, be2, stats, hB, hB_bf, N);

    // 8: W1 GEMM (relu) -> bf16 hid
    {
        dim3 grid(512 / 64, (N + 127) / 128);
        gemm_mfma_kernel<true, true, false><<<grid, 256, 0, stream>>>(
            hB_bf, nullptr, W1t, nullptr, nullptr, b1, nullptr, hid_bf, nullptr, N, Cc, 512);
    }

    // 9: W2 GEMM + BN3 stats
    {
        dim3 grid(Cc / 64, (N + 127) / 128);
        gemm_mfma_kernel<false, false, true><<<grid, 256, 0, stream>>>(
            hid_bf, nullptr, W2t, nullptr, nullptr, b2, hB, bufA, stats + 4 * Cc, N, 512, Cc);
    }

    // 10: BN3 apply in place on d_out
    bn_apply_kernel<<<(N * Cc + 255) / 256, 256, 0, stream>>>(
        bufA, bufA, g3, be3, stats + 4 * Cc, N);
}

// Round 18
// 213.189 us; speedup vs baseline: 1.2151x; 1.0540x over previous
//
#include <hip/hip_runtime.h>
#include <hip/hip_bf16.h>
#include <math.h>

#define Bc 32
#define Tc 512
#define Cc 256
#define Hc 8
#define BT (Bc * Tc)
#define EPS 1e-5f
#define LDAP 40      // LDS row stride (ushorts, 80B)
#define CSTRIDE 128  // fixed CSR row stride

typedef __bf16 bf16x8 __attribute__((ext_vector_type(8)));
typedef float f32x4 __attribute__((ext_vector_type(4)));
typedef unsigned short us8_t __attribute__((ext_vector_type(8)));

__device__ inline unsigned short f2bf(float f) {
    unsigned int u = __float_as_uint(f);
    u += 0x7fffu + ((u >> 16) & 1u);
    return (unsigned short)(u >> 16);
}
__device__ inline unsigned short f2bf_fast(float f) {
    __bf16 h = (__bf16)f;
    return __builtin_bit_cast(unsigned short, h);
}
__device__ inline float bf2f(unsigned short u) {
    return __uint_as_float((unsigned int)u << 16);
}

// Bijective XCD-chunked swizzle (m204): bid -> lid such that each XCD's
// blocks form a contiguous lid chunk. Requires nothing of nwg%8.
__device__ inline int xcd_chunk_lid(int bid, int nwg) {
    int xg = bid & 7;
    int pos = bid >> 3;
    int q = nwg >> 3;
    int r = nwg & 7;
    int base = (xg < r) ? xg * (q + 1) : r * (q + 1) + (xg - r) * q;
    return base + pos;
}

// ---------------------------------------------------------------------------
// Mega-fused prologue (unchanged)
// ---------------------------------------------------------------------------
__global__ void wcvt_fused_kernel(const float* __restrict__ Wr, const float* __restrict__ Wn,
                                  const float* __restrict__ Wq, const float* __restrict__ Wk,
                                  const float* __restrict__ Wv, const float* __restrict__ Wo,
                                  const float* __restrict__ W1, const float* __restrict__ W2,
                                  const float* __restrict__ bq, const float* __restrict__ bk,
                                  const float* __restrict__ bv,
                                  unsigned short* __restrict__ wsq, float* __restrict__ bqkv,
                                  const float* __restrict__ x, const int* __restrict__ idx,
                                  unsigned short* __restrict__ x_bf,
                                  unsigned short* __restrict__ xd_bf,
                                  int* __restrict__ bcnt, int* __restrict__ zbase,
                                  int N, int nzero4) {
    const float scale = 0.17677669529663687f;  // 1/sqrt(32)
    int gid = blockIdx.x * 256 + threadIdx.x;
    const int X0 = 656128 + N * 32;
    const int XZ = X0 + 64;
    if (gid >= XZ) {
        int j = gid - XZ;
        if (j < nzero4) {
            int4 z = {0, 0, 0, 0};
            *(int4*)&zbase[j * 4] = z;
        }
        return;
    }
    if (gid >= X0) {
        int b = gid - X0;
        if (b >= 32) return;
        int lo = 0, hi = N, v0 = b << 9;
        while (lo < hi) { int mid = (lo + hi) >> 1; if (idx[mid] < v0) lo = mid + 1; else hi = mid; }
        int s = lo;
        lo = 0; hi = N; int v1 = (b + 1) << 9;
        while (lo < hi) { int mid = (lo + hi) >> 1; if (idx[mid] < v1) lo = mid + 1; else hi = mid; }
        bcnt[b] = lo - s;
        return;
    }
    if (gid >= 656128) {
        int j = gid - 656128;
        int i = j >> 5;
        if (i >= N) return;
        int c8 = (j & 31) * 8;
        const float* sp = x + (size_t)i * Cc + c8;
        float4 f0 = *(const float4*)sp;
        float4 f1 = *(const float4*)(sp + 4);
        us8_t pk;
        pk[0] = f2bf_fast(f0.x); pk[1] = f2bf_fast(f0.y);
        pk[2] = f2bf_fast(f0.z); pk[3] = f2bf_fast(f0.w);
        pk[4] = f2bf_fast(f1.x); pk[5] = f2bf_fast(f1.y);
        pk[6] = f2bf_fast(f1.z); pk[7] = f2bf_fast(f1.w);
        *(us8_t*)&x_bf[(size_t)i * Cc + c8] = pk;
        int slot = idx[i];
        *(us8_t*)&xd_bf[(size_t)slot * Cc + c8] = pk;
        return;
    }
    if (gid >= 655360) {
        int j = gid - 655360;
        bqkv[j] = (j < 256) ? bq[j] * scale : (j < 512 ? bk[j - 256] : bv[j - 512]);
        return;
    }
    const float* src; int base, K, N_; float mul = 1.f;
    if (gid < 65536)       { src = Wr; base = 0;      K = 256; N_ = 256; }
    else if (gid < 131072) { src = Wn; base = 65536;  K = 256; N_ = 256; }
    else if (gid < 196608) { src = Wq; base = 131072; K = 256; N_ = 256; mul = scale; }
    else if (gid < 262144) { src = Wk; base = 196608; K = 256; N_ = 256; }
    else if (gid < 327680) { src = Wv; base = 262144; K = 256; N_ = 256; }
    else if (gid < 393216) { src = Wo; base = 327680; K = 256; N_ = 256; }
    else if (gid < 524288) { src = W1; base = 393216; K = 256; N_ = 512; }
    else                   { src = W2; base = 524288; K = 512; N_ = 256; }
    int loc = gid - base;
    int n = loc / K, k = loc % K;
    wsq[gid] = f2bf(src[(size_t)k * N_ + n] * mul);
}

// ---------------------------------------------------------------------------
// Direct fixed-stride CSR fill + gather (unchanged)
// ---------------------------------------------------------------------------
__global__ void fill_csr_kernel(const int* __restrict__ ei, int* __restrict__ cursor,
                                int* __restrict__ csr, int E) {
    int e = blockIdx.x * 256 + threadIdx.x;
    if (e >= E) return;
    int dst = ei[E + e];
    int pos = atomicAdd(&cursor[dst], 1);
    if (pos < CSTRIDE) csr[(size_t)dst * CSTRIDE + pos] = ei[e];
}

__global__ __launch_bounds__(256) void gather_kernel(const unsigned short* __restrict__ x_bf,
                                                     const int* __restrict__ csr,
                                                     const int* __restrict__ cursor,
                                                     unsigned short* __restrict__ agg_bf,
                                                     int N) {
    int i = blockIdx.x * 4 + (threadIdx.x >> 6);
    if (i >= N) return;
    int l4 = (threadIdx.x & 63) * 4;
    int dcount = cursor[i];
    if (dcount > CSTRIDE) dcount = CSTRIDE;
    const int* row = csr + (size_t)i * CSTRIDE;
    f32x4 a0 = {0.f, 0.f, 0.f, 0.f}, a1 = a0, a2 = a0, a3 = a0;
    int e = 0;
    for (; e + 4 <= dcount; e += 4) {
        int i0 = row[e + 0];
        int i1 = row[e + 1];
        int i2 = row[e + 2];
        int i3 = row[e + 3];
        ushort4 u0 = *(const ushort4*)(x_bf + (size_t)i0 * Cc + l4);
        ushort4 u1 = *(const ushort4*)(x_bf + (size_t)i1 * Cc + l4);
        ushort4 u2 = *(const ushort4*)(x_bf + (size_t)i2 * Cc + l4);
        ushort4 u3 = *(const ushort4*)(x_bf + (size_t)i3 * Cc + l4);
        a0[0] += bf2f(u0.x); a0[1] += bf2f(u0.y); a0[2] += bf2f(u0.z); a0[3] += bf2f(u0.w);
        a1[0] += bf2f(u1.x); a1[1] += bf2f(u1.y); a1[2] += bf2f(u1.z); a1[3] += bf2f(u1.w);
        a2[0] += bf2f(u2.x); a2[1] += bf2f(u2.y); a2[2] += bf2f(u2.z); a2[3] += bf2f(u2.w);
        a3[0] += bf2f(u3.x); a3[1] += bf2f(u3.y); a3[2] += bf2f(u3.z); a3[3] += bf2f(u3.w);
    }
    for (; e < dcount; ++e) {
        ushort4 u = *(const ushort4*)(x_bf + (size_t)row[e] * Cc + l4);
        a0[0] += bf2f(u.x); a0[1] += bf2f(u.y); a0[2] += bf2f(u.z); a0[3] += bf2f(u.w);
    }
    f32x4 s = (a0 + a1) + (a2 + a3);
    ushort4 w4;
    w4.x = f2bf_fast(s[0]); w4.y = f2bf_fast(s[1]);
    w4.z = f2bf_fast(s[2]); w4.w = f2bf_fast(s[3]);
    *(ushort4*)&agg_bf[(size_t)i * Cc + l4] = w4;
}

// ---------------------------------------------------------------------------
// GEMM body (R17 core, unchanged)
// ---------------------------------------------------------------------------
template <bool RELU, bool OUTBF16, bool STATS>
__device__ __forceinline__ void gemm_body(
    const unsigned short* __restrict__ A, const int* __restrict__ gidx,
    const unsigned short* __restrict__ Bt,
    const unsigned short* __restrict__ A2, const unsigned short* __restrict__ B2t,
    const float* __restrict__ bias, const float* __restrict__ res,
    void* __restrict__ Cout, float* __restrict__ stats, int M, int K, int Nc,
    int bx, int by, unsigned short* As, unsigned short* Bs) {
    int tid = threadIdx.x;
    int row0 = by * 128;
    int col0 = bx * 64;
    int lane = tid & 63;
    int w = tid >> 6;
    int wr = (w >> 1) * 64;
    int wc = (w & 1) * 32;
    int fr = lane & 15;
    int kk = (lane >> 4) * 8;

    f32x4 acc[4][2] = {};

    int r = tid >> 1;
    int kc = (tid & 1) * 16;
    int ql = (tid >> 2) & 15;
    int bc = ((tid >> 6) << 4) + ((ql & 3) << 1) + (((ql >> 2) & 1) << 3) + (ql >> 3);
    int bkc = (tid & 3) * 8;

    int npass = (A2 != nullptr) ? 2 : 1;
    for (int pass = 0; pass < npass; ++pass) {
        const unsigned short* Ap = pass ? A2 : A;
        const unsigned short* Bp = pass ? B2t : Bt;
        int ar = row0 + r;
        if (ar >= M) ar = M - 1;                    // clamp: finite garbage, store-guarded
        int arr = gidx ? gidx[ar] : ar;
        const unsigned short* abase = Ap + (size_t)arr * K + kc;
        const unsigned short* bbase = Bp + (size_t)(col0 + bc) * K + bkc;
        us8_t pa0 = *(const us8_t*)(abase);
        us8_t pa1 = *(const us8_t*)(abase + 8);
        us8_t pb  = *(const us8_t*)(bbase);
        for (int k0 = 0; k0 < K; k0 += 32) {
            __syncthreads();
            *(us8_t*)&As[r * LDAP + kc] = pa0;
            *(us8_t*)&As[r * LDAP + kc + 8] = pa1;
            *(us8_t*)&Bs[bc * LDAP + bkc] = pb;
            __syncthreads();
            int k1 = k0 + 32;
            if (k1 < K) {
                pa0 = *(const us8_t*)(abase + k1);
                pa1 = *(const us8_t*)(abase + k1 + 8);
                pb  = *(const us8_t*)(bbase + k1);
            }
            bf16x8 bf0 = *(bf16x8*)&Bs[(wc + fr) * LDAP + kk];
            bf16x8 bf1 = *(bf16x8*)&Bs[(wc + 16 + fr) * LDAP + kk];
#pragma unroll
            for (int fm = 0; fm < 4; ++fm) {
                bf16x8 af = *(bf16x8*)&As[(wr + fm * 16 + fr) * LDAP + kk];
                acc[fm][0] = __builtin_amdgcn_mfma_f32_16x16x32_bf16(af, bf0, acc[fm][0], 0, 0, 0);
                acc[fm][1] = __builtin_amdgcn_mfma_f32_16x16x32_bf16(af, bf1, acc[fm][1], 0, 0, 0);
            }
        }
    }
    int rq = (lane >> 4) * 4;
    float cs[2] = {0.f, 0.f}, cq[2] = {0.f, 0.f};
#pragma unroll
    for (int fm = 0; fm < 4; ++fm) {
#pragma unroll
        for (int fn = 0; fn < 2; ++fn) {
            int col = col0 + wc + fn * 16 + fr;
#pragma unroll
            for (int i = 0; i < 4; ++i) {
                int row = row0 + wr + fm * 16 + rq + i;
                if (row < M) {
                    float v = acc[fm][fn][i];
                    if (bias) v += bias[col];
                    if (res) v += res[(size_t)row * Nc + col];
                    if (RELU) v = fmaxf(v, 0.f);
                    if (OUTBF16)
                        ((unsigned short*)Cout)[(size_t)row * Nc + col] = f2bf_fast(v);
                    else
                        ((float*)Cout)[(size_t)row * Nc + col] = v;
                    if (STATS) { cs[fn] += v; cq[fn] += v * v; }
                }
            }
        }
    }
    if (STATS) {
#pragma unroll
        for (int fn = 0; fn < 2; ++fn) {
            cs[fn] += __shfl_xor(cs[fn], 16); cs[fn] += __shfl_xor(cs[fn], 32);
            cq[fn] += __shfl_xor(cq[fn], 16); cq[fn] += __shfl_xor(cq[fn], 32);
        }
        if ((lane >> 4) == 0) {
            int col = col0 + wc + fr;
            atomicAdd(&stats[col], cs[0]);
            atomicAdd(&stats[256 + col], cq[0]);
            atomicAdd(&stats[col + 16], cs[1]);
            atomicAdd(&stats[256 + col + 16], cq[1]);
        }
    }
}

// Wrapper for standalone GEMMs: XCD-chunked swizzle, cols iterate fastest
// within each XCD chunk so all col-tiles of a row panel share one L2.
template <bool RELU, bool OUTBF16, bool STATS>
__global__ __launch_bounds__(256) void gemm_mfma_kernel(
    const unsigned short* A, const int* gidx, const unsigned short* Bt,
    const unsigned short* A2, const unsigned short* B2t,
    const float* bias, const float* res, void* Cout, float* stats,
    int M, int K, int Nc) {
    __shared__ unsigned short As[128 * LDAP];
    __shared__ unsigned short Bs[64 * LDAP];
    int gx = gridDim.x;
    int nwg = gx * gridDim.y;
    int l = blockIdx.y * gx + blockIdx.x;
    int lid = xcd_chunk_lid(l, nwg);
    gemm_body<RELU, OUTBF16, STATS>(A, gidx, Bt, A2, B2t, bias, res, Cout, stats,
                                    M, K, Nc, lid % gx, lid / gx, As, Bs);
}

// Combined conv+QKV dispatch with per-range XCD-chunked swizzle
__global__ __launch_bounds__(256) void convqkv_kernel(
    const unsigned short* __restrict__ x_bf, const unsigned short* __restrict__ agg_bf,
    const unsigned short* __restrict__ Wrt, const unsigned short* __restrict__ Wnt,
    const unsigned short* __restrict__ Wqkvt,
    const float* __restrict__ b_conv, const float* __restrict__ x,
    float* __restrict__ hB, float* __restrict__ stats,
    const unsigned short* __restrict__ xd_bf, const float* __restrict__ bqkv,
    unsigned short* __restrict__ qkvb, int N, int convBlocks) {
    __shared__ unsigned short As[128 * LDAP];
    __shared__ unsigned short Bs[64 * LDAP];
    int blk = blockIdx.x;
    if (blk < convBlocks) {
        int lid = xcd_chunk_lid(blk, convBlocks);
        gemm_body<false, false, true>(x_bf, nullptr, Wrt, agg_bf, Wnt, b_conv, x,
                                      hB, stats, N, 256, 256, lid & 3, lid >> 2, As, Bs);
    } else {
        int qn = blk - convBlocks;
        // qkv range has 1536 blocks; per-XCD membership derives from global bid%8,
        // but each residue class has exactly 192 members -> qn-based chunking with
        // global-xcd grouping: use global (blk&7) as the chunk selector.
        int xg = blk & 7;
        int lid = xg * 192 + (qn >> 3);
        gemm_body<false, true, false>(xd_bf, nullptr, Wqkvt, nullptr, nullptr, bqkv, nullptr,
                                      qkvb, nullptr, BT, 256, 768, lid % 12, lid / 12, As, Bs);
    }
}

// ---------------------------------------------------------------------------
// BN applies (unchanged)
// ---------------------------------------------------------------------------
__global__ void bn_apply_kernel(const float* __restrict__ in, float* __restrict__ out,
                                const float* __restrict__ g, const float* __restrict__ be,
                                const float* __restrict__ stats, int M) {
    int gid = blockIdx.x * 256 + threadIdx.x;
    if (gid >= M * Cc) return;
    int c = gid & (Cc - 1);
    float invM = 1.f / (float)M;
    float mean = stats[c] * invM;
    float var = stats[Cc + c] * invM - mean * mean;
    float sc = g[c] * rsqrtf(var + EPS);
    out[gid] = (in[gid] - mean) * sc + be[c];
}

__global__ void bn12_apply_kernel(const float* __restrict__ hpre,
                                  const float* __restrict__ hattn,
                                  const float* __restrict__ g1, const float* __restrict__ be1,
                                  const float* __restrict__ g2, const float* __restrict__ be2,
                                  const float* __restrict__ stats,
                                  float* __restrict__ out, unsigned short* __restrict__ out_bf,
                                  int M) {
    int gid = blockIdx.x * 256 + threadIdx.x;
    if (gid >= M * Cc) return;
    int c = gid & (Cc - 1);
    float invM = 1.f / (float)M;
    float mean1 = stats[c] * invM;
    float var1 = stats[Cc + c] * invM - mean1 * mean1;
    float sc1 = g1[c] * rsqrtf(var1 + EPS);
    float mean2 = stats[2 * Cc + c] * invM;
    float var2 = stats[3 * Cc + c] * invM - mean2 * mean2;
    float sc2 = g2[c] * rsqrtf(var2 + EPS);
    float v = (hpre[gid] - mean1) * sc1 + be1[c] + (hattn[gid] - mean2) * sc2 + be2[c];
    out[gid] = v;
    out_bf[gid] = f2bf_fast(v);
}

// ---------------------------------------------------------------------------
// MFMA flash attention (unchanged)
// ---------------------------------------------------------------------------
__global__ __launch_bounds__(256) void attn_mfma_kernel(const unsigned short* __restrict__ qkvb,
                                                        const int* __restrict__ bcnt,
                                                        unsigned short* __restrict__ o_bf) {
    const int blk = ((blockIdx.x & 7) << 7) | ((int)blockIdx.x >> 3);  // XCD swizzle (1024 wgs)
    const int qt = blk & 3;
    const int bh = blk >> 2;
    const int b = bh >> 3;
    const int h = bh & 7;
    const int tid = threadIdx.x;
    const int lane = tid & 63;
    const int w = tid >> 6;
    const int fr = lane & 15;
    const int g = lane >> 4;
    const int kk = g * 8;
    const int q0 = qt * 128 + w * 32;

    __shared__ unsigned short Ks[32 * LDAP];
    __shared__ unsigned short Vt[32 * LDAP];
    __shared__ unsigned short Pl[4][2][16 * LDAP];

    const int count = bcnt[b];

    const unsigned short* qp = qkvb + (size_t)(b * Tc + q0 + fr) * 768 + h * 32 + kk;
    bf16x8 qa0 = *(const bf16x8*)qp;
    bf16x8 qa1 = *(const bf16x8*)(qp + (size_t)16 * 768);

    f32x4 op00 = {0.f, 0.f, 0.f, 0.f}, op01 = op00;
    f32x4 op10 = op00, op11 = op00;
    float l0 = 0.f, l1 = 0.f;
    float m0 = -1e30f, m1 = -1e30f;

    const int nt = (count + 31) >> 5;
    for (int t = 0; t < nt; ++t) {
        const int kbase = t * 32;
        __syncthreads();
        {
            int key = tid >> 3;
            int d4 = (tid & 7) * 4;
            const unsigned short* kp =
                qkvb + (size_t)(b * Tc + kbase + key) * 768 + 256 + h * 32 + d4;
            *(ushort4*)&Ks[key * LDAP + d4] = *(const ushort4*)kp;
        }
        {
            int vkey = tid & 31;
            int d0 = (tid >> 5) * 4;
            const unsigned short* vp =
                qkvb + (size_t)(b * Tc + kbase + vkey) * 768 + 512 + h * 32 + d0;
            ushort4 vv = *(const ushort4*)vp;
            Vt[(d0 + 0) * LDAP + vkey] = vv.x;
            Vt[(d0 + 1) * LDAP + vkey] = vv.y;
            Vt[(d0 + 2) * LDAP + vkey] = vv.z;
            Vt[(d0 + 3) * LDAP + vkey] = vv.w;
        }
        __syncthreads();

        bf16x8 ka0 = *(bf16x8*)&Ks[fr * LDAP + kk];
        bf16x8 ka1 = *(bf16x8*)&Ks[(16 + fr) * LDAP + kk];
        f32x4 z = {0.f, 0.f, 0.f, 0.f};
        f32x4 s00 = __builtin_amdgcn_mfma_f32_16x16x32_bf16(ka0, qa0, z, 0, 0, 0);
        f32x4 s10 = __builtin_amdgcn_mfma_f32_16x16x32_bf16(ka1, qa0, z, 0, 0, 0);
        f32x4 s01 = __builtin_amdgcn_mfma_f32_16x16x32_bf16(ka0, qa1, z, 0, 0, 0);
        f32x4 s11 = __builtin_amdgcn_mfma_f32_16x16x32_bf16(ka1, qa1, z, 0, 0, 0);

#pragma unroll
        for (int i = 0; i < 4; ++i) {
            bool v0 = (kbase + g * 4 + i) < count;
            bool v1 = (kbase + 16 + g * 4 + i) < count;
            s00[i] = v0 ? s00[i] : -1e30f;
            s01[i] = v0 ? s01[i] : -1e30f;
            s10[i] = v1 ? s10[i] : -1e30f;
            s11[i] = v1 ? s11[i] : -1e30f;
        }

        float r0_ = fmaxf(fmaxf(fmaxf(s00[0], s00[1]), fmaxf(s00[2], s00[3])),
                          fmaxf(fmaxf(s10[0], s10[1]), fmaxf(s10[2], s10[3])));
        r0_ = fmaxf(r0_, __shfl_xor(r0_, 16));
        r0_ = fmaxf(r0_, __shfl_xor(r0_, 32));
        float mn0 = fmaxf(m0, r0_);
        float c0 = __expf(m0 - mn0);
        m0 = mn0;
        l0 *= c0;
        float p00[4], p10[4];
#pragma unroll
        for (int i = 0; i < 4; ++i) {
            p00[i] = __expf(s00[i] - mn0);
            p10[i] = __expf(s10[i] - mn0);
            l0 += p00[i] + p10[i];
        }
        float r1_ = fmaxf(fmaxf(fmaxf(s01[0], s01[1]), fmaxf(s01[2], s01[3])),
                          fmaxf(fmaxf(s11[0], s11[1]), fmaxf(s11[2], s11[3])));
        r1_ = fmaxf(r1_, __shfl_xor(r1_, 16));
        r1_ = fmaxf(r1_, __shfl_xor(r1_, 32));
        float mn1 = fmaxf(m1, r1_);
        float c1 = __expf(m1 - mn1);
        m1 = mn1;
        l1 *= c1;
        float p01[4], p11[4];
#pragma unroll
        for (int i = 0; i < 4; ++i) {
            p01[i] = __expf(s01[i] - mn1);
            p11[i] = __expf(s11[i] - mn1);
            l1 += p01[i] + p11[i];
        }

        unsigned short* pw0 = &Pl[w][0][0];
        unsigned short* pw1 = &Pl[w][1][0];
        ushort4 q00, q10, q01, q11;
        q00.x = f2bf_fast(p00[0]); q00.y = f2bf_fast(p00[1]);
        q00.z = f2bf_fast(p00[2]); q00.w = f2bf_fast(p00[3]);
        q10.x = f2bf_fast(p10[0]); q10.y = f2bf_fast(p10[1]);
        q10.z = f2bf_fast(p10[2]); q10.w = f2bf_fast(p10[3]);
        q01.x = f2bf_fast(p01[0]); q01.y = f2bf_fast(p01[1]);
        q01.z = f2bf_fast(p01[2]); q01.w = f2bf_fast(p01[3]);
        q11.x = f2bf_fast(p11[0]); q11.y = f2bf_fast(p11[1]);
        q11.z = f2bf_fast(p11[2]); q11.w = f2bf_fast(p11[3]);
        *(ushort4*)&pw0[fr * LDAP + g * 4] = q00;
        *(ushort4*)&pw0[fr * LDAP + 16 + g * 4] = q10;
        *(ushort4*)&pw1[fr * LDAP + g * 4] = q01;
        *(ushort4*)&pw1[fr * LDAP + 16 + g * 4] = q11;

#pragma unroll
        for (int i = 0; i < 4; ++i) {
            float ci0 = __shfl(c0, g * 4 + i);
            float ci1 = __shfl(c1, g * 4 + i);
            op00[i] *= ci0; op01[i] *= ci0;
            op10[i] *= ci1; op11[i] *= ci1;
        }

        asm volatile("s_waitcnt lgkmcnt(0)" ::: "memory");
        __builtin_amdgcn_sched_barrier(0);

        bf16x8 pa0 = *(bf16x8*)&pw0[fr * LDAP + kk];
        bf16x8 pa1 = *(bf16x8*)&pw1[fr * LDAP + kk];
        bf16x8 vb0 = *(bf16x8*)&Vt[fr * LDAP + kk];
        bf16x8 vb1 = *(bf16x8*)&Vt[(16 + fr) * LDAP + kk];
        op00 = __builtin_amdgcn_mfma_f32_16x16x32_bf16(pa0, vb0, op00, 0, 0, 0);
        op01 = __builtin_amdgcn_mfma_f32_16x16x32_bf16(pa0, vb1, op01, 0, 0, 0);
        op10 = __builtin_amdgcn_mfma_f32_16x16x32_bf16(pa1, vb0, op10, 0, 0, 0);
        op11 = __builtin_amdgcn_mfma_f32_16x16x32_bf16(pa1, vb1, op11, 0, 0, 0);
    }

    l0 += __shfl_xor(l0, 16); l0 += __shfl_xor(l0, 32);
    l1 += __shfl_xor(l1, 16); l1 += __shfl_xor(l1, 32);
    float inv0 = 1.f / l0;
    float inv1 = 1.f / l1;
#pragma unroll
    for (int i = 0; i < 4; ++i) {
        float li0 = __shfl(inv0, g * 4 + i);
        float li1 = __shfl(inv1, g * 4 + i);
        size_t row0 = (size_t)(b * Tc + q0 + g * 4 + i);
        size_t row1 = row0 + 16;
        o_bf[row0 * Cc + h * 32 + fr] = f2bf_fast(op00[i] * li0);
        o_bf[row0 * Cc + h * 32 + 16 + fr] = f2bf_fast(op01[i] * li0);
        o_bf[row1 * Cc + h * 32 + fr] = f2bf_fast(op10[i] * li1);
        o_bf[row1 * Cc + h * 32 + 16 + fr] = f2bf_fast(op11[i] * li1);
    }
}

// ---------------------------------------------------------------------------
// Launch (10 dispatches)
// ---------------------------------------------------------------------------
extern "C" void kernel_launch(void* const* d_in, const int* in_sizes, int n_in,
                              void* d_out, int out_size, void* d_ws, size_t ws_size,
                              hipStream_t stream) {
    const float* x      = (const float*)d_in[0];
    const int*   ei     = (const int*)d_in[1];
    const int*   idx    = (const int*)d_in[2];
    const float* W_root = (const float*)d_in[4];
    const float* W_nbr  = (const float*)d_in[5];
    const float* b_conv = (const float*)d_in[6];
    const float* Wq     = (const float*)d_in[7];
    const float* Wk     = (const float*)d_in[8];
    const float* Wv     = (const float*)d_in[9];
    const float* bq     = (const float*)d_in[10];
    const float* bk     = (const float*)d_in[11];
    const float* bv     = (const float*)d_in[12];
    const float* Wo     = (const float*)d_in[13];
    const float* bo     = (const float*)d_in[14];
    const float* W1     = (const float*)d_in[15];
    const float* b1     = (const float*)d_in[16];
    const float* W2     = (const float*)d_in[17];
    const float* b2     = (const float*)d_in[18];
    const float* g1     = (const float*)d_in[19];
    const float* be1    = (const float*)d_in[20];
    const float* g2     = (const float*)d_in[21];
    const float* be2    = (const float*)d_in[22];
    const float* g3     = (const float*)d_in[23];
    const float* be3    = (const float*)d_in[24];

    const int N = in_sizes[0] / Cc;
    const int E = in_sizes[1] / 2;

    // Workspace layout
    float* ws = (float*)d_ws;
    float* hB    = ws;                                       // N*C f32 (h_pre -> out1)
    float* bqkv  = hB + (size_t)N * Cc;                      // 768
    unsigned short* wsq    = (unsigned short*)(bqkv + 768);  // 655360
    unsigned short* x_bf   = wsq + 655360;                   // N*C
    unsigned short* hB_bf  = x_bf + (size_t)N * Cc;          // N*C
    unsigned short* hid_bf = hB_bf + (size_t)N * Cc;         // N*2C
    unsigned short* xd_bf  = hid_bf + (size_t)N * 2 * Cc;    // BT*C (also attn out)
    unsigned short* qkvb   = xd_bf + (size_t)BT * Cc;        // BT*768
    int*   bcnt   = (int*)(qkvb + (size_t)BT * 768);         // 32
    float* stats  = (float*)(bcnt + 32);                     // 6*C, start of zeroed region
    int*   cursor = (int*)(stats + 6 * Cc);                  // N (degree counters), zeroed
    int*   csr    = cursor + N;                              // N*CSTRIDE
    float* bufA   = (float*)d_out;                           // N*C scratch
    unsigned short* agg_bf = (unsigned short*)d_out;
    unsigned short* ao = xd_bf;

    const unsigned short* Wrt   = wsq;
    const unsigned short* Wnt   = wsq + 65536;
    const unsigned short* Wqkvt = wsq + 131072;
    const unsigned short* Wot   = wsq + 327680;
    const unsigned short* W1t   = wsq + 393216;
    const unsigned short* W2t   = wsq + 524288;

    const int nzero = 6 * Cc + N;          // stats floats + cursor ints (contiguous)
    const int nzero4 = (nzero + 3) / 4;

    // 1: mega-fused prologue
    {
        int total = 656128 + N * 32 + 64 + nzero4;
        wcvt_fused_kernel<<<(total + 255) / 256, 256, 0, stream>>>(
            W_root, W_nbr, Wq, Wk, Wv, Wo, W1, W2, bq, bk, bv, wsq, bqkv,
            x, idx, x_bf, xd_bf, bcnt, (int*)stats, N, nzero4);
    }

    // 2: direct CSR fill (cursor -> degree)
    fill_csr_kernel<<<(E + 255) / 256, 256, 0, stream>>>(ei, cursor, csr, E);

    // 3: gather (agg -> bf16 in d_out region)
    gather_kernel<<<(N + 3) / 4, 256, 0, stream>>>(x_bf, csr, cursor, agg_bf, N);

    // 4: combined conv GEMM (+BN1 stats) and QKV GEMM (->bf16), XCD-swizzled
    {
        int convBlocks = 4 * ((N + 127) / 128);
        int qkvBlocks = 12 * (BT / 128);
        convqkv_kernel<<<convBlocks + qkvBlocks, 256, 0, stream>>>(
            x_bf, agg_bf, Wrt, Wnt, Wqkvt, b_conv, x, hB, stats,
            xd_bf, bqkv, qkvb, N, convBlocks);
    }

    // 5: attention
    attn_mfma_kernel<<<Bc * Hc * 4, 256, 0, stream>>>(qkvb, bcnt, ao);

    // 6: Wo GEMM + BN2 stats
    {
        dim3 grid(Cc / 64, (N + 127) / 128);
        gemm_mfma_kernel<false, false, true><<<grid, 256, 0, stream>>>(
            ao, idx, Wot, nullptr, nullptr, bo, x, bufA, stats + 2 * Cc, N, Cc, Cc);
    }

    // 7: fused BN1+BN2 apply -> out1 (f32 hB + bf16 hB_bf)
    bn12_apply_kernel<<<(N * Cc + 255) / 256, 256, 0, stream>>>(
        hB, bufA, g1, be1, g2, be2, stats, hB, hB_bf, N);

    // 8: W1 GEMM (relu) -> bf16 hid
    {
        dim3 grid(512 / 64, (N + 127) / 128);
        gemm_mfma_kernel<true, true, false><<<grid, 256, 0, stream>>>(
            hB_bf, nullptr, W1t, nullptr, nullptr, b1, nullptr, hid_bf, nullptr, N, Cc, 512);
    }

    // 9: W2 GEMM + BN3 stats
    {
        dim3 grid(Cc / 64, (N + 127) / 128);
        gemm_mfma_kernel<false, false, true><<<grid, 256, 0, stream>>>(
            hid_bf, nullptr, W2t, nullptr, nullptr, b2, hB, bufA, stats + 4 * Cc, N, 512, Cc);
    }

    // 10: BN3 apply in place on d_out
    bn_apply_kernel<<<(N * Cc + 255) / 256, 256, 0, stream>>>(
        bufA, bufA, g3, be3, stats + 4 * Cc, N);
}